// Round 3
// baseline (15430.312 us; speedup 1.0000x reference)
//
#include <hip/hip_runtime.h>
#include <cstdint>
#include <cstddef>

#define B_ 128
#define P_ 196
#define ENC_ 2048
#define A_ 512
#define E_ 512
#define D_ 512
#define V_ 10000
#define L_ 52
#define T_ 51
#define NBLK 256u
#define SL_ 8          // split-K slices for gates GEMM (K=3072 -> 384/slice)

using short8 = __attribute__((ext_vector_type(8))) short;
using short4v = __attribute__((ext_vector_type(4))) short;
using floatx4 = __attribute__((ext_vector_type(4))) float;

__device__ __forceinline__ float sigf(float x){ return 1.f/(1.f+expf(-x)); }

__device__ __forceinline__ unsigned short f2bf(float f){
  unsigned int u = __float_as_uint(f);
  unsigned int r = (u + 0x7fffu + ((u >> 16) & 1u)) >> 16;
  return (unsigned short)r;
}
__device__ __forceinline__ float bf2f(unsigned short u){
  return __uint_as_float(((unsigned int)u) << 16);
}

// ---------------- sort (stable descending by length) ----------------
__global__ void sort_kernel(const int* __restrict__ cap_len, const int* __restrict__ caps,
                            int* __restrict__ order, int* __restrict__ dec_len,
                            int* __restrict__ caps_sorted,
                            float* __restrict__ out_caps, float* __restrict__ out_declen){
  __shared__ int len_s[B_];
  int i = threadIdx.x;
  len_s[i] = cap_len[i];
  __syncthreads();
  int li = len_s[i];
  int pos = 0;
  for (int j = 0; j < B_; j++){
    int lj = len_s[j];
    pos += (lj > li) || (lj == li && j < i);
  }
  order[pos] = i;
  dec_len[pos] = li - 1;
  out_declen[pos] = (float)(li - 1);
  for (int l = 0; l < L_; l++){
    int v = caps[i * L_ + l];
    caps_sorted[pos * L_ + l] = v;
    out_caps[pos * L_ + l] = (float)v;
  }
}

// ---------------- enc gather + fp32->bf16 ----------------
__global__ void gather_kernel(const float* __restrict__ enc, const int* __restrict__ order,
                              unsigned short* __restrict__ enc_s){
  int b = blockIdx.y;
  int i = (blockIdx.x * 256 + threadIdx.x) * 4;
  const float4 v = *(const float4*)(enc + (size_t)order[b] * (P_ * ENC_) + i);
  short4v r;
  r[0] = (short)f2bf(v.x); r[1] = (short)f2bf(v.y);
  r[2] = (short)f2bf(v.z); r[3] = (short)f2bf(v.w);
  *(short4v*)(enc_s + (size_t)b * (P_ * ENC_) + i) = r;
}

// ---------------- weight conversion/packing + state init ----------------
__global__ void prep_kernel(const float* __restrict__ We, const float* __restrict__ Wd,
                            const float* __restrict__ Wbeta,
                            const float* __restrict__ W_ih, const float* __restrict__ W_hh,
                            const float* __restrict__ Wfc,
                            const float* __restrict__ bd, const float* __restrict__ bbeta,
                            const float* __restrict__ b_ih, const float* __restrict__ b_hh,
                            unsigned short* __restrict__ We_b, unsigned short* __restrict__ Wpre_b,
                            unsigned short* __restrict__ Wg_b, unsigned short* __restrict__ Wfc_b,
                            float* __restrict__ bias_pre, float* __restrict__ bias_g,
                            float* __restrict__ h, float* __restrict__ c,
                            unsigned short* __restrict__ h_b, unsigned short* __restrict__ xh,
                            unsigned int* __restrict__ bar){
  unsigned int idx = blockIdx.x * blockDim.x + threadIdx.x;
  unsigned int stride = gridDim.x * blockDim.x;
  if (idx == 0) bar[0] = 0u;
  // We_b: 512x2048 direct
  for (unsigned int i = idx; i < 512u * 2048u; i += stride) We_b[i] = f2bf(We[i]);
  // Wpre_b = [Wd(512x512) ; Wbeta(2048x512)] flat concat (K matches)
  for (unsigned int i = idx; i < 2560u * 512u; i += stride)
    Wpre_b[i] = f2bf(i < 512u * 512u ? Wd[i] : Wbeta[i - 512u * 512u]);
  // Wg_b rows: [W_ih row(2560) | W_hh row(512)] -> 2048 x 3072
  for (unsigned int i = idx; i < 2048u * 3072u; i += stride){
    unsigned int j = i / 3072u, k = i - j * 3072u;
    Wg_b[i] = f2bf(k < 2560u ? W_ih[j * 2560u + k] : W_hh[j * 512u + (k - 2560u)]);
  }
  // Wfc_b: 10000x512 direct
  for (unsigned int i = idx; i < 10000u * 512u; i += stride) Wfc_b[i] = f2bf(Wfc[i]);
  // biases
  for (unsigned int i = idx; i < 2560u; i += stride) bias_pre[i] = (i < 512u) ? bd[i] : bbeta[i - 512u];
  for (unsigned int i = idx; i < 2048u; i += stride) bias_g[i] = b_ih[i] + b_hh[i];
  // state init
  for (unsigned int i = idx; i < (unsigned)B_ * D_; i += stride){
    h[i] = 0.f; c[i] = 0.f; h_b[i] = 0;
    unsigned int b = i >> 9, d = i & 511u;
    xh[(size_t)b * 3072 + 2560 + d] = 0;
  }
}

// ---------------- 256-thread GEMM core (setup/tail kernels) ----------------
#define GEMM_CORE(Aptr, LDA, Bptr, LDB, KDIM, NCLAMP)                         \
  int tid = threadIdx.x; int lane = tid & 63; int w = tid >> 6;               \
  const floatx4 vzero = {0.f,0.f,0.f,0.f};                                    \
  floatx4 acc[4][4];                                                          \
  _Pragma("unroll") for (int i_=0;i_<4;i_++)                                  \
  _Pragma("unroll") for (int j_=0;j_<4;j_++) acc[i_][j_]=vzero;               \
  int mbase=(w&1)<<6, nbase=(w>>1)<<6;                                        \
  int fr=lane&15, fk=(lane>>4)<<3;                                            \
  for (int k0=0;k0<(KDIM);k0+=32){                                            \
    _Pragma("unroll") for (int r_=0;r_<2;r_++){                               \
      int chunk=r_*256+tid; int row=chunk>>2, kc=(chunk&3)<<3;                \
      short8 av=*(const short8*)((Aptr)+(size_t)(m0+row)*(LDA)+k0+kc);        \
      int bn=n0+row; if(bn>(NCLAMP)) bn=(NCLAMP);                             \
      short8 bv=*(const short8*)((Bptr)+(size_t)bn*(LDB)+k0+kc);              \
      *(short8*)&As[chunk*8]=av; *(short8*)&Bs[chunk*8]=bv; }                 \
    __syncthreads();                                                          \
    short8 af[4], bfrag[4];                                                   \
    _Pragma("unroll") for (int i_=0;i_<4;i_++){                               \
      af[i_]=*(const short8*)&As[(mbase+i_*16+fr)*32+fk];                     \
      bfrag[i_]=*(const short8*)&Bs[(nbase+i_*16+fr)*32+fk]; }                \
    _Pragma("unroll") for (int mi_=0;mi_<4;mi_++)                             \
    _Pragma("unroll") for (int ni_=0;ni_<4;ni_++)                             \
      acc[mi_][ni_]=__builtin_amdgcn_mfma_f32_16x16x32_bf16(af[mi_],bfrag[ni_],acc[mi_][ni_],0,0,0); \
    __syncthreads(); }

// ---------------- 1024-thread GEMM core (persistent-kernel phases) ----------
// 16 waves in 4x4 grid of 32x32 sub-tiles; 2x2 16x16 fragments per wave.
#define GEMM_CORE_1024(Aptr, LDA, Bptr, LDB, K0, K1, NCLAMP)                  \
  int tid = threadIdx.x; int lane = tid & 63; int w = tid >> 6;               \
  const floatx4 vzero = {0.f,0.f,0.f,0.f};                                    \
  floatx4 acc[2][2];                                                          \
  acc[0][0]=vzero; acc[0][1]=vzero; acc[1][0]=vzero; acc[1][1]=vzero;         \
  int mbase=(w&3)<<5, nbase=(w>>2)<<5;                                        \
  int fr=lane&15, fk=(lane>>4)<<3;                                            \
  for (int k0=(K0); k0<(K1); k0+=32){                                         \
    { int cid = tid & 511; int row = cid >> 2, kc = (cid & 3) << 3;           \
      if (tid < 512){                                                         \
        short8 av = *(const short8*)((Aptr)+(size_t)(m0+row)*(LDA)+k0+kc);    \
        *(short8*)&As[cid*8] = av;                                            \
      } else {                                                                \
        int bn = n0 + row; if (bn > (NCLAMP)) bn = (NCLAMP);                  \
        short8 bv = *(const short8*)((Bptr)+(size_t)bn*(LDB)+k0+kc);          \
        *(short8*)&Bs[cid*8] = bv; } }                                        \
    __syncthreads();                                                          \
    short8 af[2], bfrag[2];                                                   \
    af[0]=*(const short8*)&As[(mbase+fr)*32+fk];                              \
    af[1]=*(const short8*)&As[(mbase+16+fr)*32+fk];                           \
    bfrag[0]=*(const short8*)&Bs[(nbase+fr)*32+fk];                           \
    bfrag[1]=*(const short8*)&Bs[(nbase+16+fr)*32+fk];                        \
    acc[0][0]=__builtin_amdgcn_mfma_f32_16x16x32_bf16(af[0],bfrag[0],acc[0][0],0,0,0); \
    acc[0][1]=__builtin_amdgcn_mfma_f32_16x16x32_bf16(af[0],bfrag[1],acc[0][1],0,0,0); \
    acc[1][0]=__builtin_amdgcn_mfma_f32_16x16x32_bf16(af[1],bfrag[0],acc[1][0],0,0,0); \
    acc[1][1]=__builtin_amdgcn_mfma_f32_16x16x32_bf16(af[1],bfrag[1],acc[1][1],0,0,0); \
    __syncthreads(); }

// ---------------- enc_att = enc_s @ We^T + be -> bf16 ----------------
__launch_bounds__(256)
__global__ void gemm_encatt(const unsigned short* __restrict__ A,
                            const unsigned short* __restrict__ Bm,
                            const float* __restrict__ bias,
                            unsigned short* __restrict__ Cb){
  __shared__ unsigned short As[128*32];
  __shared__ unsigned short Bs[128*32];
  int m0 = blockIdx.y * 128, n0 = blockIdx.x * 128;
  GEMM_CORE(A, ENC_, Bm, ENC_, ENC_, 511)
#pragma unroll
  for (int mi = 0; mi < 4; mi++)
#pragma unroll
    for (int ni = 0; ni < 4; ni++){
      int col = n0 + nbase + ni*16 + fr;
      float bb = bias[col];
      int rb = m0 + mbase + mi*16 + ((lane>>4)<<2);
#pragma unroll
      for (int r = 0; r < 4; r++)
        Cb[(size_t)(rb + r) * A_ + col] = f2bf(acc[mi][ni][r] + bb);
    }
}

// ---------------- device-scope grid barrier ----------------
__device__ __forceinline__ void gsync(unsigned int* bar, unsigned int target){
  __syncthreads();
  if (threadIdx.x == 0){
    __threadfence();
    __hip_atomic_fetch_add(bar, 1u, __ATOMIC_RELEASE, __HIP_MEMORY_SCOPE_AGENT);
    while (__hip_atomic_load(bar, __ATOMIC_ACQUIRE, __HIP_MEMORY_SCOPE_AGENT) < target)
      __builtin_amdgcn_s_sleep(2);
    __threadfence();
  }
  __syncthreads();
}

// ---------------- persistent loop kernel: 51 steps, 4 phases each ----------
// grid = 256 blocks x 1024 threads, 1 block/CU (guaranteed co-resident).
__launch_bounds__(1024, 1)
__global__ void loop_kernel(const unsigned short* __restrict__ Wpre_b,
                            const float* __restrict__ bias_pre,
                            const unsigned short* __restrict__ Wg_b,
                            const float* __restrict__ bias_g,
                            const unsigned short* __restrict__ enc_att,
                            const unsigned short* __restrict__ enc_s,
                            const float* __restrict__ wf, const float* __restrict__ bfp,
                            const float* __restrict__ emb, const int* __restrict__ caps_sorted,
                            const int* __restrict__ dec_len,
                            unsigned short* __restrict__ h_b,
                            float* __restrict__ out_pre,
                            unsigned short* __restrict__ xh,
                            float* __restrict__ gpart,
                            float* __restrict__ h, float* __restrict__ c,
                            unsigned short* __restrict__ hnew_b,
                            unsigned int* __restrict__ bar){
  __shared__ unsigned short As[128*32];
  __shared__ unsigned short Bs[128*32];
  __shared__ float sc[P_];
  __shared__ float al[P_];
  __shared__ float red[256];
  __shared__ float4 part[4][256];
  int blk = blockIdx.x;
  unsigned int ep = 0;

  for (int t = 0; t < T_; t++){
    // ---- phase A: out_pre = h_b @ Wpre^T + bias_pre  (20 jobs, K=512) ----
    if (blk < 20){
      int m0 = 0, n0 = blk * 128;
      GEMM_CORE_1024(h_b, D_, Wpre_b, D_, 0, D_, 2559)
#pragma unroll
      for (int mi = 0; mi < 2; mi++)
#pragma unroll
        for (int ni = 0; ni < 2; ni++){
          int col = n0 + nbase + ni*16 + fr;
          float bb = bias_pre[col];
          int rb = mbase + mi*16 + ((lane>>4)<<2);
#pragma unroll
          for (int r = 0; r < 4; r++)
            out_pre[(size_t)(rb + r) * 2560 + col] = acc[mi][ni][r] + bb;
        }
    }
    ep++; gsync(bar, ep * NBLK);

    // ---- phase B: attention -> xh[512:2560] = gate*awe ; xh[0:512] = emb ----
    {
      int tid = threadIdx.x;
      int b = blk >> 1, bx = blk & 1;
      int wid = tid >> 6, lane = tid & 63;
      float dav[8], wfv[8];
      {
        const float* dp = out_pre + (size_t)b * 2560 + lane * 8;
        *(float4*)&dav[0] = *(const float4*)(dp);
        *(float4*)&dav[4] = *(const float4*)(dp + 4);
        *(float4*)&wfv[0] = *(const float4*)(wf + lane * 8);
        *(float4*)&wfv[4] = *(const float4*)(wf + lane * 8 + 4);
      }
      float bfv = bfp[0];
      for (int p = wid; p < P_; p += 16){
        short8 e = *(const short8*)(enc_att + ((size_t)b * P_ + p) * A_ + lane * 8);
        float s = 0.f;
#pragma unroll
        for (int j = 0; j < 8; j++){
          float v = bf2f((unsigned short)e[j]) + dav[j];
          s += fmaxf(v, 0.f) * wfv[j];
        }
#pragma unroll
        for (int off = 32; off > 0; off >>= 1) s += __shfl_down(s, off);
        if (lane == 0) sc[p] = s + bfv;
      }
      __syncthreads();
      // softmax over 196
      if (tid < 256) red[tid] = (tid < P_) ? sc[tid] : -1e30f;
      __syncthreads();
      for (int s = 128; s > 0; s >>= 1){ if (tid < s) red[tid] = fmaxf(red[tid], red[tid + s]); __syncthreads(); }
      float mx = red[0];
      __syncthreads();
      float ex = 0.f;
      if (tid < 256){ ex = (tid < P_) ? expf(sc[tid] - mx) : 0.f; red[tid] = ex; }
      __syncthreads();
      for (int s = 128; s > 0; s >>= 1){ if (tid < s) red[tid] += red[tid + s]; __syncthreads(); }
      float inv = 1.f / red[0];
      if (tid < P_) al[tid] = ex * inv;
      __syncthreads();
      // awe with 4-way p split
      int pg = tid >> 8, et = tid & 255;
      int e0 = bx * 1024 + et * 4;
      const unsigned short* encb = enc_s + (size_t)b * (P_ * ENC_) + e0;
      float a0 = 0.f, a1 = 0.f, a2 = 0.f, a3 = 0.f;
      int pbeg = pg * 49;
#pragma unroll 7
      for (int p = pbeg; p < pbeg + 49; p++){
        float a = al[p];
        short4v v = *(const short4v*)(encb + (size_t)p * ENC_);
        a0 += a * bf2f((unsigned short)v[0]);
        a1 += a * bf2f((unsigned short)v[1]);
        a2 += a * bf2f((unsigned short)v[2]);
        a3 += a * bf2f((unsigned short)v[3]);
      }
      float4 pv; pv.x = a0; pv.y = a1; pv.z = a2; pv.w = a3;
      part[pg][et] = pv;
      __syncthreads();
      if (pg == 0){
        float4 s0 = part[0][et], s1 = part[1][et], s2 = part[2][et], s3 = part[3][et];
        float4 g4 = *(const float4*)(out_pre + (size_t)b * 2560 + 512 + e0);
        short4v r;
        r[0] = (short)f2bf(sigf(g4.x) * (s0.x + s1.x + s2.x + s3.x));
        r[1] = (short)f2bf(sigf(g4.y) * (s0.y + s1.y + s2.y + s3.y));
        r[2] = (short)f2bf(sigf(g4.z) * (s0.z + s1.z + s2.z + s3.z));
        r[3] = (short)f2bf(sigf(g4.w) * (s0.w + s1.w + s2.w + s3.w));
        *(short4v*)(xh + (size_t)b * 3072 + 512 + e0) = r;
      }
      if (bx == 1 && tid < 512){
        int tok = caps_sorted[b * L_ + t];
        xh[(size_t)b * 3072 + tid] = f2bf(emb[(size_t)tok * E_ + tid]);
      }
    }
    ep++; gsync(bar, ep * NBLK);

    // ---- phase C: gpart[sl] = xh @ Wg^T (K-slice)  (128 jobs, 12 iters) ----
    if (blk < 16 * SL_){
      int tile = blk & 15, slice = blk >> 4;
      int m0 = 0, n0 = tile * 128;
      int kb = slice * (3072 / SL_);
      GEMM_CORE_1024(xh, 3072, Wg_b, 3072, kb, kb + (3072 / SL_), 2047)
      float* gp = gpart + (size_t)slice * (B_ * 2048);
#pragma unroll
      for (int mi = 0; mi < 2; mi++)
#pragma unroll
        for (int ni = 0; ni < 2; ni++){
          int col = n0 + nbase + ni*16 + fr;
          int rb = mbase + mi*16 + ((lane>>4)<<2);
#pragma unroll
          for (int r = 0; r < 4; r++)
            gp[(size_t)(rb + r) * 2048 + col] = acc[mi][ni][r];
        }
    }
    ep++; gsync(bar, ep * NBLK);

    // ---- phase D: LSTM pointwise (blocks 0..63) ----
    {
      int idx = blk * 1024 + threadIdx.x;
      if (idx < B_ * D_){
        int b = idx >> 9, d = idx & 511;
        float gs[4];
#pragma unroll
        for (int g = 0; g < 4; g++){
          int cc = g * 512 + d;
          float s = bias_g[cc];
#pragma unroll
          for (int sl = 0; sl < SL_; sl++)
            s += gpart[((size_t)sl * B_ + b) * 2048 + cc];
          gs[g] = s;
        }
        float cold = c[idx];
        float cn = sigf(gs[1]) * cold + sigf(gs[0]) * tanhf(gs[2]);
        float hn = sigf(gs[3]) * tanhf(cn);
        bool act = t < dec_len[b];
        float hv = act ? hn : h[idx];
        float cv = act ? cn : cold;
        h[idx] = hv; c[idx] = cv;
        unsigned short hvb = f2bf(hv);
        h_b[idx] = hvb;
        xh[(size_t)b * 3072 + 2560 + d] = hvb;
        hnew_b[(size_t)t * (B_ * D_) + idx] = f2bf(hn);
      }
    }
    ep++; gsync(bar, ep * NBLK);
  }
}

// ---------------- preds GEMM with LDS-staged coalesced epilogue ----------------
__launch_bounds__(256)
__global__ void gemm_preds(const unsigned short* __restrict__ A,    // hnew_b 6528x512
                           const unsigned short* __restrict__ Bm,   // Wfc_b 10000x512
                           const float* __restrict__ bias,
                           float* __restrict__ Cf,
                           const int* __restrict__ dec_len){
  __shared__ __attribute__((aligned(16))) char smem[4 * 64 * 68 * 4];
  unsigned short* As = (unsigned short*)smem;
  unsigned short* Bs = (unsigned short*)(smem + 8192);
  int m0 = blockIdx.y * 128, n0 = blockIdx.x * 128;
  GEMM_CORE(A, D_, Bm, D_, D_, V_ - 1)
  float* Cs = (float*)smem + (size_t)w * (64 * 68);
#pragma unroll
  for (int mi = 0; mi < 4; mi++)
#pragma unroll
    for (int ni = 0; ni < 4; ni++){
      int lc = ni*16 + fr;
      int col = n0 + nbase + lc;
      float bb = bias[col < V_ ? col : V_ - 1];
#pragma unroll
      for (int r = 0; r < 4; r++){
        int lr = mi*16 + ((lane>>4)<<2) + r;
        Cs[lr * 68 + lc] = acc[mi][ni][r] + bb;
      }
    }
#pragma unroll
  for (int rd = 0; rd < 16; rd++){
    int lr = rd * 4 + (lane >> 4);
    int m = m0 + mbase + lr;
    int tt = m >> 7, b = m & 127;
    int col = n0 + nbase + fr * 4;
    floatx4 v = *(const floatx4*)&Cs[lr * 68 + fr * 4];
    if (tt >= dec_len[b]){ v[0]=0.f; v[1]=0.f; v[2]=0.f; v[3]=0.f; }
    if (col < V_)
      __builtin_nontemporal_store(v, (floatx4*)(Cf + ((size_t)b * T_ + tt) * V_ + col));
  }
}

extern "C" void kernel_launch(void* const* d_in, const int* in_sizes, int n_in,
                              void* d_out, int out_size, void* d_ws, size_t ws_size,
                              hipStream_t stream) {
  const float* encoder_out = (const float*)d_in[0];
  const int*   caps        = (const int*)d_in[1];
  const int*   cap_len     = (const int*)d_in[2];
  const float* emb         = (const float*)d_in[3];
  const float* We          = (const float*)d_in[4];
  const float* be          = (const float*)d_in[5];
  const float* Wd          = (const float*)d_in[6];
  const float* bd          = (const float*)d_in[7];
  const float* wf          = (const float*)d_in[8];
  const float* bf          = (const float*)d_in[9];
  const float* W_ih        = (const float*)d_in[10];
  const float* b_ih        = (const float*)d_in[11];
  const float* W_hh        = (const float*)d_in[12];
  const float* b_hh        = (const float*)d_in[13];
  const float* Wbeta       = (const float*)d_in[14];
  const float* bbeta       = (const float*)d_in[15];
  const float* Wfc         = (const float*)d_in[16];
  const float* bfc         = (const float*)d_in[17];

  float* out_preds  = (float*)d_out;
  float* out_caps   = out_preds + (size_t)B_ * T_ * V_;
  float* out_declen = out_caps + (size_t)B_ * L_;

  char* w = (char*)d_ws;
  auto alloc = [&](size_t bytes) -> void* {
    void* p = (void*)w;
    w += (bytes + 255) & ~(size_t)255;
    return p;
  };
  int*   order       = (int*)alloc(B_ * 4);
  int*   dec_len     = (int*)alloc(B_ * 4);
  int*   caps_sorted = (int*)alloc((size_t)B_ * L_ * 4);
  unsigned short* enc_s   = (unsigned short*)alloc((size_t)B_ * P_ * ENC_ * 2);
  unsigned short* We_b    = (unsigned short*)alloc((size_t)512 * 2048 * 2);
  unsigned short* Wpre_b  = (unsigned short*)alloc((size_t)2560 * 512 * 2);
  unsigned short* Wg_b    = (unsigned short*)alloc((size_t)2048 * 3072 * 2);
  unsigned short* Wfc_b   = (unsigned short*)alloc((size_t)10000 * 512 * 2);
  unsigned short* enc_att = (unsigned short*)alloc((size_t)B_ * P_ * A_ * 2);
  float* bias_pre    = (float*)alloc(2560 * 4);
  float* bias_g      = (float*)alloc(2048 * 4);
  float* out_pre     = (float*)alloc((size_t)B_ * 2560 * 4);
  unsigned short* xh = (unsigned short*)alloc((size_t)B_ * 3072 * 2);
  float* gpart       = (float*)alloc((size_t)SL_ * B_ * 2048 * 4);
  float* h           = (float*)alloc((size_t)B_ * D_ * 4);
  float* c           = (float*)alloc((size_t)B_ * D_ * 4);
  unsigned short* h_b = (unsigned short*)alloc((size_t)B_ * D_ * 2);
  unsigned short* hnew_b = (unsigned short*)alloc((size_t)T_ * B_ * D_ * 2);
  unsigned int* bar  = (unsigned int*)alloc(256);

  sort_kernel<<<1, 128, 0, stream>>>(cap_len, caps, order, dec_len, caps_sorted, out_caps, out_declen);
  gather_kernel<<<dim3(392, 128), 256, 0, stream>>>(encoder_out, order, enc_s);
  prep_kernel<<<2048, 256, 0, stream>>>(We, Wd, Wbeta, W_ih, W_hh, Wfc, bd, bbeta, b_ih, b_hh,
                                        We_b, Wpre_b, Wg_b, Wfc_b, bias_pre, bias_g,
                                        h, c, h_b, xh, bar);

  // enc_att = enc_s @ We^T + be -> bf16 : M=25088, N=512, K=2048
  gemm_encatt<<<dim3(4, 196), 256, 0, stream>>>(enc_s, We_b, be, enc_att);

  // persistent kernel: whole t-loop with internal grid barriers
  loop_kernel<<<NBLK, 1024, 0, stream>>>(Wpre_b, bias_pre, Wg_b, bias_g, enc_att, enc_s,
                                         wf, bf, emb, caps_sorted, dec_len,
                                         h_b, out_pre, xh, gpart, h, c, hnew_b, bar);

  // preds: (T*B, V) = hnew @ Wfc^T + bfc, masked + scattered to (B,T,V)
  gemm_preds<<<dim3(79, 51), 256, 0, stream>>>(hnew_b, Wfc_b, bfc, out_preds, dec_len);
}

// Round 4
// 6904.895 us; speedup vs baseline: 2.2347x; 2.2347x over previous
//
#include <hip/hip_runtime.h>
#include <cstdint>
#include <cstddef>

#define B_ 128
#define P_ 196
#define ENC_ 2048
#define A_ 512
#define E_ 512
#define D_ 512
#define V_ 10000
#define L_ 52
#define T_ 51

using short8 = __attribute__((ext_vector_type(8))) short;
using short4v = __attribute__((ext_vector_type(4))) short;
using floatx4 = __attribute__((ext_vector_type(4))) float;

__device__ __forceinline__ float sigf(float x){ return 1.f/(1.f+expf(-x)); }

__device__ __forceinline__ unsigned short f2bf(float f){
  unsigned int u = __float_as_uint(f);
  unsigned int r = (u + 0x7fffu + ((u >> 16) & 1u)) >> 16;
  return (unsigned short)r;
}
__device__ __forceinline__ float bf2f(unsigned short u){
  return __uint_as_float(((unsigned int)u) << 16);
}

// ---------------- sort (stable descending by length) ----------------
__global__ void sort_kernel(const int* __restrict__ cap_len, const int* __restrict__ caps,
                            int* __restrict__ order, int* __restrict__ dec_len,
                            int* __restrict__ caps_sorted,
                            float* __restrict__ out_caps, float* __restrict__ out_declen){
  __shared__ int len_s[B_];
  int i = threadIdx.x;
  len_s[i] = cap_len[i];
  __syncthreads();
  int li = len_s[i];
  int pos = 0;
  for (int j = 0; j < B_; j++){
    int lj = len_s[j];
    pos += (lj > li) || (lj == li && j < i);
  }
  order[pos] = i;
  dec_len[pos] = li - 1;
  out_declen[pos] = (float)(li - 1);
  for (int l = 0; l < L_; l++){
    int v = caps[i * L_ + l];
    caps_sorted[pos * L_ + l] = v;
    out_caps[pos * L_ + l] = (float)v;
  }
}

// ---------------- enc gather + fp32->bf16 ----------------
__global__ void gather_kernel(const float* __restrict__ enc, const int* __restrict__ order,
                              unsigned short* __restrict__ enc_s){
  int b = blockIdx.y;
  int i = (blockIdx.x * 256 + threadIdx.x) * 4;
  const float4 v = *(const float4*)(enc + (size_t)order[b] * (P_ * ENC_) + i);
  short4v r;
  r[0] = (short)f2bf(v.x); r[1] = (short)f2bf(v.y);
  r[2] = (short)f2bf(v.z); r[3] = (short)f2bf(v.w);
  *(short4v*)(enc_s + (size_t)b * (P_ * ENC_) + i) = r;
}

// ---------------- weight conversion/packing + state init ----------------
__global__ void prep_kernel(const float* __restrict__ We, const float* __restrict__ Wd,
                            const float* __restrict__ Wbeta,
                            const float* __restrict__ W_ih, const float* __restrict__ W_hh,
                            const float* __restrict__ Wfc,
                            const float* __restrict__ bd, const float* __restrict__ bbeta,
                            const float* __restrict__ b_ih, const float* __restrict__ b_hh,
                            unsigned short* __restrict__ We_b, unsigned short* __restrict__ Wpre_b,
                            unsigned short* __restrict__ Wg_b, unsigned short* __restrict__ Wfc_b,
                            float* __restrict__ bias_pre, float* __restrict__ bias_g,
                            float* __restrict__ hA, float* __restrict__ hB,
                            float* __restrict__ cA, float* __restrict__ cB,
                            unsigned short* __restrict__ xh){
  unsigned int idx = blockIdx.x * blockDim.x + threadIdx.x;
  unsigned int stride = gridDim.x * blockDim.x;
  // We_b: 512x2048 direct
  for (unsigned int i = idx; i < 512u * 2048u; i += stride) We_b[i] = f2bf(We[i]);
  // Wpre_b = [Wd(512x512) ; Wbeta(2048x512)] flat concat (K matches)
  for (unsigned int i = idx; i < 2560u * 512u; i += stride)
    Wpre_b[i] = f2bf(i < 512u * 512u ? Wd[i] : Wbeta[i - 512u * 512u]);
  // Wg_b rows: [W_ih row(2560) | W_hh row(512)] -> 2048 x 3072
  for (unsigned int i = idx; i < 2048u * 3072u; i += stride){
    unsigned int j = i / 3072u, k = i - j * 3072u;
    Wg_b[i] = f2bf(k < 2560u ? W_ih[j * 2560u + k] : W_hh[j * 512u + (k - 2560u)]);
  }
  // Wfc_b: 10000x512 direct
  for (unsigned int i = idx; i < 10000u * 512u; i += stride) Wfc_b[i] = f2bf(Wfc[i]);
  // biases
  for (unsigned int i = idx; i < 2560u; i += stride) bias_pre[i] = (i < 512u) ? bd[i] : bbeta[i - 512u];
  for (unsigned int i = idx; i < 2048u; i += stride) bias_g[i] = b_ih[i] + b_hh[i];
  // state init (both ping-pong buffers)
  for (unsigned int i = idx; i < (unsigned)B_ * D_; i += stride){
    hA[i] = 0.f; hB[i] = 0.f; cA[i] = 0.f; cB[i] = 0.f;
    unsigned int b = i >> 9, d = i & 511u;
    xh[(size_t)b * 3072 + 2560 + d] = 0;
  }
}

// ---------------- 256-thread GEMM core: C(128x128) = A(MxK) @ B(NxK)^T -------
#define GEMM_CORE(Aptr, LDA, Bptr, LDB, KDIM, NCLAMP)                         \
  int tid = threadIdx.x; int lane = tid & 63; int w = tid >> 6;               \
  const floatx4 vzero = {0.f,0.f,0.f,0.f};                                    \
  floatx4 acc[4][4];                                                          \
  _Pragma("unroll") for (int i_=0;i_<4;i_++)                                  \
  _Pragma("unroll") for (int j_=0;j_<4;j_++) acc[i_][j_]=vzero;               \
  int mbase=(w&1)<<6, nbase=(w>>1)<<6;                                        \
  int fr=lane&15, fk=(lane>>4)<<3;                                            \
  for (int k0=0;k0<(KDIM);k0+=32){                                            \
    _Pragma("unroll") for (int r_=0;r_<2;r_++){                               \
      int chunk=r_*256+tid; int row=chunk>>2, kc=(chunk&3)<<3;                \
      short8 av=*(const short8*)((Aptr)+(size_t)(m0+row)*(LDA)+k0+kc);        \
      int bn=n0+row; if(bn>(NCLAMP)) bn=(NCLAMP);                             \
      short8 bv=*(const short8*)((Bptr)+(size_t)bn*(LDB)+k0+kc);              \
      *(short8*)&As[chunk*8]=av; *(short8*)&Bs[chunk*8]=bv; }                 \
    __syncthreads();                                                          \
    short8 af[4], bfrag[4];                                                   \
    _Pragma("unroll") for (int i_=0;i_<4;i_++){                               \
      af[i_]=*(const short8*)&As[(mbase+i_*16+fr)*32+fk];                     \
      bfrag[i_]=*(const short8*)&Bs[(nbase+i_*16+fr)*32+fk]; }                \
    _Pragma("unroll") for (int mi_=0;mi_<4;mi_++)                             \
    _Pragma("unroll") for (int ni_=0;ni_<4;ni_++)                             \
      acc[mi_][ni_]=__builtin_amdgcn_mfma_f32_16x16x32_bf16(af[mi_],bfrag[ni_],acc[mi_][ni_],0,0,0); \
    __syncthreads(); }

// ---------------- enc_att = enc_s @ We^T + be -> bf16 ----------------
__launch_bounds__(256)
__global__ void gemm_encatt(const unsigned short* __restrict__ A,
                            const unsigned short* __restrict__ Bm,
                            const float* __restrict__ bias,
                            unsigned short* __restrict__ Cb){
  __shared__ unsigned short As[128*32];
  __shared__ unsigned short Bs[128*32];
  int m0 = blockIdx.y * 128, n0 = blockIdx.x * 128;
  GEMM_CORE(A, ENC_, Bm, ENC_, ENC_, 511)
#pragma unroll
  for (int mi = 0; mi < 4; mi++)
#pragma unroll
    for (int ni = 0; ni < 4; ni++){
      int col = n0 + nbase + ni*16 + fr;
      float bb = bias[col];
      int rb = m0 + mbase + mi*16 + ((lane>>4)<<2);
#pragma unroll
      for (int r = 0; r < 4; r++)
        Cb[(size_t)(rb + r) * A_ + col] = f2bf(acc[mi][ni][r] + bb);
    }
}

// ---------------- fused LSTM(t-1) + pre-GEMM(t) ----------------
// grid 20 x 1024. Each block: LSTM pointwise (redundant) -> LDS A-tile (bf16),
// then out_pre[:, n0:n0+128] = h @ Wpre^T + bias (full K=512, A LDS-resident).
// block 0 also writes h/c (ping-pong out), xh h-part, hnew_b[t-1].
// t==0: h == 0, skip LSTM. t==T_: LSTM only (tail).
__launch_bounds__(1024, 1)
__global__ void fused_pre(const float* __restrict__ gates,
                          const float* __restrict__ h_in, const float* __restrict__ c_in,
                          float* __restrict__ h_out, float* __restrict__ c_out,
                          const unsigned short* __restrict__ Wpre_b,
                          const float* __restrict__ bias_pre,
                          float* __restrict__ out_pre,
                          unsigned short* __restrict__ xh,
                          unsigned short* __restrict__ hnew_b,
                          const int* __restrict__ dec_len, int t){
  __shared__ unsigned short Ah[128 * 520];   // 128 x 512 bf16, stride 520 (pad)
  __shared__ unsigned short Bs[128 * 72];    // 128 x 64 bf16, stride 72 (pad)
  int tid = threadIdx.x;
  if (t == 0){
    for (int i = tid; i < B_ * D_; i += 1024){
      int b = i >> 9, d = i & 511;
      Ah[b * 520 + d] = 0;
    }
  } else {
    bool writer = (blockIdx.x == 0);
    for (int i = tid; i < B_ * D_; i += 1024){
      int b = i >> 9, d = i & 511;
      const float* gr = gates + (size_t)b * 2048 + d;
      float i_ = gr[0], f_ = gr[512], g_ = gr[1024], o_ = gr[1536];
      float cold = c_in[i];
      float cn = sigf(f_) * cold + sigf(i_) * tanhf(g_);
      float hn = sigf(o_) * tanhf(cn);
      bool act = (t - 1) < dec_len[b];
      float hv = act ? hn : h_in[i];
      float cv = act ? cn : cold;
      unsigned short hvb = f2bf(hv);
      Ah[b * 520 + d] = hvb;
      if (writer){
        h_out[i] = hv; c_out[i] = cv;
        xh[(size_t)b * 3072 + 2560 + d] = hvb;
        hnew_b[(size_t)(t - 1) * (B_ * D_) + i] = f2bf(hn);
      }
    }
  }
  __syncthreads();
  if (t >= T_) return;   // tail launch: LSTM only

  int n0 = blockIdx.x * 128;
  int lane = tid & 63, w = tid >> 6;
  const floatx4 vzero = {0.f, 0.f, 0.f, 0.f};
  floatx4 acc[2][2] = {{vzero, vzero}, {vzero, vzero}};
  int mbase = (w & 3) << 5, nbase = (w >> 2) << 5;
  int fr = lane & 15, fk = (lane >> 4) << 3;
  for (int k0 = 0; k0 < 512; k0 += 64){
    { int row = tid >> 3, kc = (tid & 7) << 3;
      *(short8*)&Bs[row * 72 + kc] =
        *(const short8*)(Wpre_b + (size_t)(n0 + row) * 512 + k0 + kc); }
    __syncthreads();
#pragma unroll
    for (int ks = 0; ks < 2; ks++){
      int kk = k0 + ks * 32;
      short8 a0 = *(const short8*)&Ah[(mbase + fr) * 520 + kk + fk];
      short8 a1 = *(const short8*)&Ah[(mbase + 16 + fr) * 520 + kk + fk];
      short8 b0 = *(const short8*)&Bs[(nbase + fr) * 72 + ks * 32 + fk];
      short8 b1 = *(const short8*)&Bs[(nbase + 16 + fr) * 72 + ks * 32 + fk];
      acc[0][0] = __builtin_amdgcn_mfma_f32_16x16x32_bf16(a0, b0, acc[0][0], 0, 0, 0);
      acc[0][1] = __builtin_amdgcn_mfma_f32_16x16x32_bf16(a0, b1, acc[0][1], 0, 0, 0);
      acc[1][0] = __builtin_amdgcn_mfma_f32_16x16x32_bf16(a1, b0, acc[1][0], 0, 0, 0);
      acc[1][1] = __builtin_amdgcn_mfma_f32_16x16x32_bf16(a1, b1, acc[1][1], 0, 0, 0);
    }
    __syncthreads();
  }
#pragma unroll
  for (int mi = 0; mi < 2; mi++)
#pragma unroll
    for (int ni = 0; ni < 2; ni++){
      int col = n0 + nbase + ni*16 + fr;
      float bb = bias_pre[col];
      int rb = mbase + mi*16 + ((lane>>4)<<2);
#pragma unroll
      for (int r = 0; r < 4; r++)
        out_pre[(size_t)(rb + r) * 2560 + col] = acc[mi][ni][r] + bb;
    }
}

// ---------------- fused attention: scores + softmax + awe + gate -> xh ------
// grid (2, 128) x 1024; also inits gates = bias_g for this step's split-K GEMM.
__launch_bounds__(1024)
__global__ void attn_kernel(const unsigned short* __restrict__ enc_att,
                            const unsigned short* __restrict__ enc_s,
                            const float* __restrict__ out_pre,
                            const float* __restrict__ wf, const float* __restrict__ bfp,
                            const float* __restrict__ emb, const int* __restrict__ caps_sorted,
                            unsigned short* __restrict__ xh,
                            float* __restrict__ gates, const float* __restrict__ bias_g,
                            int t){
  __shared__ float sc[P_];
  __shared__ float al[P_];
  __shared__ float red[256];
  __shared__ float4 part[4][256];
  int b = blockIdx.y, bx = blockIdx.x, tid = threadIdx.x;

  int gid = (b * 2 + bx) * 1024 + tid;   // covers exactly B_*2048
  gates[gid] = bias_g[gid & 2047];

  // ---- phase 1: scores ----
  int wid = tid >> 6, lane = tid & 63;
  float dav[8], wfv[8];
  {
    const float* dp = out_pre + (size_t)b * 2560 + lane * 8;
    *(float4*)&dav[0] = *(const float4*)(dp);
    *(float4*)&dav[4] = *(const float4*)(dp + 4);
    *(float4*)&wfv[0] = *(const float4*)(wf + lane * 8);
    *(float4*)&wfv[4] = *(const float4*)(wf + lane * 8 + 4);
  }
  float bfv = bfp[0];
  for (int p = wid; p < P_; p += 16){
    short8 e = *(const short8*)(enc_att + ((size_t)b * P_ + p) * A_ + lane * 8);
    float s = 0.f;
#pragma unroll
    for (int j = 0; j < 8; j++){
      float v = bf2f((unsigned short)e[j]) + dav[j];
      s += fmaxf(v, 0.f) * wfv[j];
    }
#pragma unroll
    for (int off = 32; off > 0; off >>= 1) s += __shfl_down(s, off);
    if (lane == 0) sc[p] = s + bfv;
  }
  __syncthreads();

  // ---- phase 2: softmax over 196 ----
  if (tid < 256) red[tid] = (tid < P_) ? sc[tid] : -1e30f;
  __syncthreads();
  for (int s = 128; s > 0; s >>= 1){ if (tid < s) red[tid] = fmaxf(red[tid], red[tid + s]); __syncthreads(); }
  float mx = red[0];
  __syncthreads();
  float ex = 0.f;
  if (tid < 256){ ex = (tid < P_) ? expf(sc[tid] - mx) : 0.f; red[tid] = ex; }
  __syncthreads();
  for (int s = 128; s > 0; s >>= 1){ if (tid < s) red[tid] += red[tid + s]; __syncthreads(); }
  float inv = 1.f / red[0];
  if (tid < P_) al[tid] = ex * inv;
  __syncthreads();

  // ---- phase 3: awe with 4-way p split ----
  int pg = tid >> 8, et = tid & 255;
  int e0 = bx * 1024 + et * 4;
  const unsigned short* encb = enc_s + (size_t)b * (P_ * ENC_) + e0;
  float a0 = 0.f, a1 = 0.f, a2 = 0.f, a3 = 0.f;
  int pbeg = pg * 49;
#pragma unroll 7
  for (int p = pbeg; p < pbeg + 49; p++){
    float a = al[p];
    short4v v = *(const short4v*)(encb + (size_t)p * ENC_);
    a0 += a * bf2f((unsigned short)v[0]);
    a1 += a * bf2f((unsigned short)v[1]);
    a2 += a * bf2f((unsigned short)v[2]);
    a3 += a * bf2f((unsigned short)v[3]);
  }
  float4 pv; pv.x = a0; pv.y = a1; pv.z = a2; pv.w = a3;
  part[pg][et] = pv;
  __syncthreads();
  if (pg == 0){
    float4 s0 = part[0][et], s1 = part[1][et], s2 = part[2][et], s3 = part[3][et];
    float4 g4 = *(const float4*)(out_pre + (size_t)b * 2560 + 512 + e0);
    short4v r;
    r[0] = (short)f2bf(sigf(g4.x) * (s0.x + s1.x + s2.x + s3.x));
    r[1] = (short)f2bf(sigf(g4.y) * (s0.y + s1.y + s2.y + s3.y));
    r[2] = (short)f2bf(sigf(g4.z) * (s0.z + s1.z + s2.z + s3.z));
    r[3] = (short)f2bf(sigf(g4.w) * (s0.w + s1.w + s2.w + s3.w));
    *(short4v*)(xh + (size_t)b * 3072 + 512 + e0) = r;
  }
  if (bx == 1 && tid < 512){
    int tok = caps_sorted[b * L_ + t];
    xh[(size_t)b * 3072 + tid] = f2bf(emb[(size_t)tok * E_ + tid]);
  }
}

// ---------------- gates GEMM: split-K=8, atomic fp32 epilogue ----------------
// gates (bias pre-init by attn) += xh(128x3072) @ Wg(2048x3072)^T  slice
__launch_bounds__(256)
__global__ void gemm_gates(const unsigned short* __restrict__ Axh,
                           const unsigned short* __restrict__ Bm,
                           float* __restrict__ Cf){
  __shared__ unsigned short As[128*32];
  __shared__ unsigned short Bs[128*32];
  int m0 = 0, n0 = blockIdx.x * 128;
  int kb = blockIdx.z * 384;
  const unsigned short* A = Axh + kb;
  const unsigned short* B2 = Bm + kb;
  GEMM_CORE(A, 3072, B2, 3072, 384, 2047)
#pragma unroll
  for (int mi = 0; mi < 4; mi++)
#pragma unroll
    for (int ni = 0; ni < 4; ni++){
      int col = n0 + nbase + ni*16 + fr;
      int rb = mbase + mi*16 + ((lane>>4)<<2);
#pragma unroll
      for (int r = 0; r < 4; r++)
        atomicAdd(&Cf[(size_t)(rb + r) * 2048 + col], acc[mi][ni][r]);
    }
}

// ---------------- preds GEMM: XCD-chunked swizzle + LDS-staged stores --------
__launch_bounds__(256)
__global__ void gemm_preds(const unsigned short* __restrict__ A,    // hnew_b 6528x512
                           const unsigned short* __restrict__ Bm,   // Wfc_b 10000x512
                           const float* __restrict__ bias,
                           float* __restrict__ Cf,
                           const int* __restrict__ dec_len){
  __shared__ __attribute__((aligned(16))) char smem[4 * 64 * 68 * 4];
  unsigned short* As = (unsigned short*)smem;
  unsigned short* Bs = (unsigned short*)(smem + 8192);
  // bijective XCD-chunked remap: each XCD gets contiguous wg-range, m fastest
  int bid = blockIdx.y * 79 + blockIdx.x;          // 0..4028
  const int TOT = 79 * 51, q = TOT / 8, r_ = TOT % 8;
  int xcd = bid & 7, idx = bid >> 3;
  int wg = (xcd < r_) ? xcd * (q + 1) + idx : r_ * (q + 1) + (xcd - r_) * q + idx;
  int nt = wg / 51, mt = wg - nt * 51;
  int m0 = mt * 128, n0 = nt * 128;
  GEMM_CORE(A, D_, Bm, D_, D_, V_ - 1)
  float* Cs = (float*)smem + (size_t)w * (64 * 68);
#pragma unroll
  for (int mi = 0; mi < 4; mi++)
#pragma unroll
    for (int ni = 0; ni < 4; ni++){
      int lc = ni*16 + fr;
      int col = n0 + nbase + lc;
      float bb = bias[col < V_ ? col : V_ - 1];
#pragma unroll
      for (int r = 0; r < 4; r++){
        int lr = mi*16 + ((lane>>4)<<2) + r;
        Cs[lr * 68 + lc] = acc[mi][ni][r] + bb;
      }
    }
#pragma unroll
  for (int rd = 0; rd < 16; rd++){
    int lr = rd * 4 + (lane >> 4);
    int m = m0 + mbase + lr;
    int tt = m >> 7, b = m & 127;
    int col = n0 + nbase + fr * 4;
    floatx4 v = *(const floatx4*)&Cs[lr * 68 + fr * 4];
    if (tt >= dec_len[b]){ v[0]=0.f; v[1]=0.f; v[2]=0.f; v[3]=0.f; }
    if (col < V_)
      __builtin_nontemporal_store(v, (floatx4*)(Cf + ((size_t)b * T_ + tt) * V_ + col));
  }
}

extern "C" void kernel_launch(void* const* d_in, const int* in_sizes, int n_in,
                              void* d_out, int out_size, void* d_ws, size_t ws_size,
                              hipStream_t stream) {
  const float* encoder_out = (const float*)d_in[0];
  const int*   caps        = (const int*)d_in[1];
  const int*   cap_len     = (const int*)d_in[2];
  const float* emb         = (const float*)d_in[3];
  const float* We          = (const float*)d_in[4];
  const float* be          = (const float*)d_in[5];
  const float* Wd          = (const float*)d_in[6];
  const float* bd          = (const float*)d_in[7];
  const float* wf          = (const float*)d_in[8];
  const float* bf          = (const float*)d_in[9];
  const float* W_ih        = (const float*)d_in[10];
  const float* b_ih        = (const float*)d_in[11];
  const float* W_hh        = (const float*)d_in[12];
  const float* b_hh        = (const float*)d_in[13];
  const float* Wbeta       = (const float*)d_in[14];
  const float* bbeta       = (const float*)d_in[15];
  const float* Wfc         = (const float*)d_in[16];
  const float* bfc         = (const float*)d_in[17];

  float* out_preds  = (float*)d_out;
  float* out_caps   = out_preds + (size_t)B_ * T_ * V_;
  float* out_declen = out_caps + (size_t)B_ * L_;

  char* w = (char*)d_ws;
  auto alloc = [&](size_t bytes) -> void* {
    void* p = (void*)w;
    w += (bytes + 255) & ~(size_t)255;
    return p;
  };
  int*   order       = (int*)alloc(B_ * 4);
  int*   dec_len     = (int*)alloc(B_ * 4);
  int*   caps_sorted = (int*)alloc((size_t)B_ * L_ * 4);
  unsigned short* enc_s   = (unsigned short*)alloc((size_t)B_ * P_ * ENC_ * 2);
  unsigned short* We_b    = (unsigned short*)alloc((size_t)512 * 2048 * 2);
  unsigned short* Wpre_b  = (unsigned short*)alloc((size_t)2560 * 512 * 2);
  unsigned short* Wg_b    = (unsigned short*)alloc((size_t)2048 * 3072 * 2);
  unsigned short* Wfc_b   = (unsigned short*)alloc((size_t)10000 * 512 * 2);
  unsigned short* enc_att = (unsigned short*)alloc((size_t)B_ * P_ * A_ * 2);
  float* bias_pre    = (float*)alloc(2560 * 4);
  float* bias_g      = (float*)alloc(2048 * 4);
  float* out_pre     = (float*)alloc((size_t)B_ * 2560 * 4);
  unsigned short* xh = (unsigned short*)alloc((size_t)B_ * 3072 * 2);
  float* gates       = (float*)alloc((size_t)B_ * 2048 * 4);
  float* hA          = (float*)alloc((size_t)B_ * D_ * 4);
  float* hB          = (float*)alloc((size_t)B_ * D_ * 4);
  float* cA          = (float*)alloc((size_t)B_ * D_ * 4);
  float* cB          = (float*)alloc((size_t)B_ * D_ * 4);
  unsigned short* hnew_b = (unsigned short*)alloc((size_t)T_ * B_ * D_ * 2);

  sort_kernel<<<1, 128, 0, stream>>>(cap_len, caps, order, dec_len, caps_sorted, out_caps, out_declen);
  gather_kernel<<<dim3(392, 128), 256, 0, stream>>>(encoder_out, order, enc_s);
  prep_kernel<<<2048, 256, 0, stream>>>(We, Wd, Wbeta, W_ih, W_hh, Wfc, bd, bbeta, b_ih, b_hh,
                                        We_b, Wpre_b, Wg_b, Wfc_b, bias_pre, bias_g,
                                        hA, hB, cA, cB, xh);

  // enc_att = enc_s @ We^T + be -> bf16 : M=25088, N=512, K=2048
  gemm_encatt<<<dim3(4, 196), 256, 0, stream>>>(enc_s, We_b, be, enc_att);

  float *hi = hA, *ho = hB, *ci = cA, *co = cB;
  for (int t = 0; t < T_; t++){
    // LSTM(t-1) + out_pre = h @ [Wd;Wbeta]^T + bias (A-tile LDS-resident)
    fused_pre<<<20, 1024, 0, stream>>>(gates, hi, ci, ho, co, Wpre_b, bias_pre,
                                       out_pre, xh, hnew_b, dec_len, t);

    // attention -> xh = [emb | gate*awe | (h from fused_pre)]; gates = bias_g
    attn_kernel<<<dim3(2, B_), 1024, 0, stream>>>(enc_att, enc_s, out_pre, wf, bf,
                                                  emb, caps_sorted, xh, gates, bias_g, t);

    // gates += xh @ [W_ih|W_hh]^T  (split-K=8, atomic)
    gemm_gates<<<dim3(16, 1, 8), 256, 0, stream>>>(xh, Wg_b, gates);

    float* tmp = hi; hi = ho; ho = tmp;
    tmp = ci; ci = co; co = tmp;
  }
  // tail: LSTM(T-1) only -> hnew_b[50]
  fused_pre<<<1, 1024, 0, stream>>>(gates, hi, ci, ho, co, Wpre_b, bias_pre,
                                    out_pre, xh, hnew_b, dec_len, T_);

  // preds: (T*B, V) = hnew @ Wfc^T + bfc, masked + scattered to (B,T,V)
  gemm_preds<<<dim3(79, 51), 256, 0, stream>>>(hnew_b, Wfc_b, bfc, out_preds, dec_len);
}

// Round 5
// 4737.291 us; speedup vs baseline: 3.2572x; 1.4576x over previous
//
#include <hip/hip_runtime.h>
#include <cstdint>
#include <cstddef>

#define B_ 128
#define P_ 196
#define ENC_ 2048
#define A_ 512
#define E_ 512
#define D_ 512
#define V_ 10000
#define L_ 52
#define T_ 51

using short8 = __attribute__((ext_vector_type(8))) short;
using short4v = __attribute__((ext_vector_type(4))) short;
using floatx4 = __attribute__((ext_vector_type(4))) float;

__device__ __forceinline__ float sigf(float x){ return 1.f/(1.f+expf(-x)); }

__device__ __forceinline__ unsigned short f2bf(float f){
  unsigned int u = __float_as_uint(f);
  unsigned int r = (u + 0x7fffu + ((u >> 16) & 1u)) >> 16;
  return (unsigned short)r;
}
__device__ __forceinline__ float bf2f(unsigned short u){
  return __uint_as_float(((unsigned int)u) << 16);
}

// gate-interleaved column mapping: cc in [0,2048) <-> (d, gate)
// cc bits: [10:7]=T [6]=H [5:4]=G [3:0]=L ; d = T*32+H*16+L, gate=G
__device__ __forceinline__ int ild_d(int cc){ return ((cc>>7)<<5) | (((cc>>6)&1)<<4) | (cc&15); }
__device__ __forceinline__ int ild_gate(int cc){ return (cc>>4)&3; }

// ---------------- sort (stable descending by length) ----------------
__global__ void sort_kernel(const int* __restrict__ cap_len, const int* __restrict__ caps,
                            int* __restrict__ order, int* __restrict__ dec_len,
                            int* __restrict__ caps_sorted,
                            float* __restrict__ out_caps, float* __restrict__ out_declen){
  __shared__ int len_s[B_];
  int i = threadIdx.x;
  len_s[i] = cap_len[i];
  __syncthreads();
  int li = len_s[i];
  int pos = 0;
  for (int j = 0; j < B_; j++){
    int lj = len_s[j];
    pos += (lj > li) || (lj == li && j < i);
  }
  order[pos] = i;
  dec_len[pos] = li - 1;
  out_declen[pos] = (float)(li - 1);
  for (int l = 0; l < L_; l++){
    int v = caps[i * L_ + l];
    caps_sorted[pos * L_ + l] = v;
    out_caps[pos * L_ + l] = (float)v;
  }
}

// ---------------- enc gather + fp32->bf16 ----------------
__global__ void gather_kernel(const float* __restrict__ enc, const int* __restrict__ order,
                              unsigned short* __restrict__ enc_s){
  int b = blockIdx.y;
  int i = (blockIdx.x * 256 + threadIdx.x) * 4;
  const float4 v = *(const float4*)(enc + (size_t)order[b] * (P_ * ENC_) + i);
  short4v r;
  r[0] = (short)f2bf(v.x); r[1] = (short)f2bf(v.y);
  r[2] = (short)f2bf(v.z); r[3] = (short)f2bf(v.w);
  *(short4v*)(enc_s + (size_t)b * (P_ * ENC_) + i) = r;
}

// ---------------- weight conversion/packing + state init ----------------
__global__ void prep_kernel(const float* __restrict__ We, const float* __restrict__ Wd,
                            const float* __restrict__ Wbeta,
                            const float* __restrict__ W_ih, const float* __restrict__ W_hh,
                            const float* __restrict__ Wfc,
                            const float* __restrict__ bd, const float* __restrict__ bbeta,
                            const float* __restrict__ b_ih, const float* __restrict__ b_hh,
                            unsigned short* __restrict__ We_b, unsigned short* __restrict__ Wpre_b,
                            unsigned short* __restrict__ Wg_b, unsigned short* __restrict__ Wfc_b,
                            float* __restrict__ bias_pre, float* __restrict__ bias_g,
                            float* __restrict__ out_pre,
                            float* __restrict__ h, float* __restrict__ c,
                            unsigned short* __restrict__ h_b, unsigned short* __restrict__ xh,
                            int* __restrict__ cnt){
  unsigned int idx = blockIdx.x * blockDim.x + threadIdx.x;
  unsigned int stride = gridDim.x * blockDim.x;
  if (idx < 16u) cnt[idx] = 0;
  // We_b: 512x2048 direct
  for (unsigned int i = idx; i < 512u * 2048u; i += stride) We_b[i] = f2bf(We[i]);
  // Wpre_b = [Wd(512x512) ; Wbeta(2048x512)] flat concat (K matches)
  for (unsigned int i = idx; i < 2560u * 512u; i += stride)
    Wpre_b[i] = f2bf(i < 512u * 512u ? Wd[i] : Wbeta[i - 512u * 512u]);
  // Wg_b rows gate-interleaved: row cc -> orig gate*512+d ; K = [W_ih(2560)|W_hh(512)]
  for (unsigned int i = idx; i < 2048u * 3072u; i += stride){
    unsigned int cc = i / 3072u, k = i - cc * 3072u;
    int orig = ild_gate((int)cc) * 512 + ild_d((int)cc);
    Wg_b[i] = f2bf(k < 2560u ? W_ih[(size_t)orig * 2560u + k] : W_hh[(size_t)orig * 512u + (k - 2560u)]);
  }
  // Wfc_b: 10000x512 direct
  for (unsigned int i = idx; i < 10000u * 512u; i += stride) Wfc_b[i] = f2bf(Wfc[i]);
  // biases (bias_g gate-interleaved)
  for (unsigned int i = idx; i < 2560u; i += stride) bias_pre[i] = (i < 512u) ? bd[i] : bbeta[i - 512u];
  for (unsigned int i = idx; i < 2048u; i += stride){
    int orig = ild_gate((int)i) * 512 + ild_d((int)i);
    bias_g[i] = b_ih[orig] + b_hh[orig];
  }
  // out_pre init (t=0) = bias broadcast
  for (unsigned int i = idx; i < (unsigned)B_ * 2560u; i += stride){
    unsigned int k = i % 2560u;
    out_pre[i] = (k < 512u) ? bd[k] : bbeta[k - 512u];
  }
  // state init
  for (unsigned int i = idx; i < (unsigned)B_ * D_; i += stride){
    h[i] = 0.f; c[i] = 0.f; h_b[i] = 0;
    unsigned int b = i >> 9, d = i & 511u;
    xh[(size_t)b * 3072 + 2560 + d] = 0;
  }
}

// ---------------- 256-thread GEMM core: C(128x128) = A(MxK) @ B(NxK)^T -------
#define GEMM_CORE(Aptr, LDA, Bptr, LDB, KDIM, NCLAMP)                         \
  int tid = threadIdx.x; int lane = tid & 63; int w = tid >> 6;               \
  const floatx4 vzero = {0.f,0.f,0.f,0.f};                                    \
  floatx4 acc[4][4];                                                          \
  _Pragma("unroll") for (int i_=0;i_<4;i_++)                                  \
  _Pragma("unroll") for (int j_=0;j_<4;j_++) acc[i_][j_]=vzero;               \
  int mbase=(w&1)<<6, nbase=(w>>1)<<6;                                        \
  int fr=lane&15, fk=(lane>>4)<<3;                                            \
  for (int k0=0;k0<(KDIM);k0+=32){                                            \
    _Pragma("unroll") for (int r_=0;r_<2;r_++){                               \
      int chunk=r_*256+tid; int row=chunk>>2, kc=(chunk&3)<<3;                \
      short8 av=*(const short8*)((Aptr)+(size_t)(m0+row)*(LDA)+k0+kc);        \
      int bn=n0+row; if(bn>(NCLAMP)) bn=(NCLAMP);                             \
      short8 bv=*(const short8*)((Bptr)+(size_t)bn*(LDB)+k0+kc);              \
      *(short8*)&As[chunk*8]=av; *(short8*)&Bs[chunk*8]=bv; }                 \
    __syncthreads();                                                          \
    short8 af[4], bfrag[4];                                                   \
    _Pragma("unroll") for (int i_=0;i_<4;i_++){                               \
      af[i_]=*(const short8*)&As[(mbase+i_*16+fr)*32+fk];                     \
      bfrag[i_]=*(const short8*)&Bs[(nbase+i_*16+fr)*32+fk]; }                \
    _Pragma("unroll") for (int mi_=0;mi_<4;mi_++)                             \
    _Pragma("unroll") for (int ni_=0;ni_<4;ni_++)                             \
      acc[mi_][ni_]=__builtin_amdgcn_mfma_f32_16x16x32_bf16(af[mi_],bfrag[ni_],acc[mi_][ni_],0,0,0); \
    __syncthreads(); }

// ---------------- generic GEMM (epi 0: atomic fp32; epi 1: bf16 + bias) ------
__launch_bounds__(256)
__global__ void gemm_bf16(const unsigned short* __restrict__ A, int lda,
                          const unsigned short* __restrict__ Bm, int ldb,
                          const float* __restrict__ bias,
                          float* __restrict__ Cf, unsigned short* __restrict__ Cb, int ldc,
                          int N, int ksz, int epi)
{
  __shared__ unsigned short As[128 * 32];
  __shared__ unsigned short Bs[128 * 32];
  int m0 = blockIdx.y * 128, n0 = blockIdx.x * 128;
  int kb = blockIdx.z * ksz;
  const unsigned short* Ap = A + kb;
  const unsigned short* Bp = Bm + kb;
  GEMM_CORE(Ap, lda, Bp, ldb, ksz, N - 1)
#pragma unroll
  for (int mi = 0; mi < 4; mi++)
#pragma unroll
    for (int ni = 0; ni < 4; ni++){
      floatx4 v = acc[mi][ni];
      int col = n0 + nbase + ni * 16 + fr;
      int rb = m0 + mbase + mi * 16 + ((lane >> 4) << 2);
      if (epi == 0){
#pragma unroll
        for (int r = 0; r < 4; r++)
          atomicAdd(&Cf[(size_t)(rb + r) * ldc + col], v[r]);
      } else {
        float bb = bias[col];
#pragma unroll
        for (int r = 0; r < 4; r++)
          Cb[(size_t)(rb + r) * ldc + col] = f2bf(v[r] + bb);
      }
    }
}

// ---------------- fused attention: scores + softmax + awe + gate -> xh ------
// grid (2, 128) x 1024; also: init gates=bias_g, zero cnt, copy h_b -> xh h-part.
__launch_bounds__(1024)
__global__ void attn_kernel(const unsigned short* __restrict__ enc_att,
                            const unsigned short* __restrict__ enc_s,
                            const float* __restrict__ out_pre,
                            const float* __restrict__ wf, const float* __restrict__ bfp,
                            const float* __restrict__ emb, const int* __restrict__ caps_sorted,
                            const unsigned short* __restrict__ h_b,
                            unsigned short* __restrict__ xh,
                            float* __restrict__ gates, const float* __restrict__ bias_g,
                            int* __restrict__ cnt, int t){
  __shared__ float sc[P_];
  __shared__ float al[P_];
  __shared__ float red[256];
  __shared__ float4 part[4][256];
  int b = blockIdx.y, bx = blockIdx.x, tid = threadIdx.x;

  if (b == 0 && bx == 0 && tid < 16) cnt[tid] = 0;

  int gid = (b * 2 + bx) * 1024 + tid;   // covers exactly B_*2048
  gates[gid] = bias_g[gid & 2047];

  // ---- phase 1: scores ----
  int wid = tid >> 6, lane = tid & 63;
  float dav[8], wfv[8];
  {
    const float* dp = out_pre + (size_t)b * 2560 + lane * 8;
    *(float4*)&dav[0] = *(const float4*)(dp);
    *(float4*)&dav[4] = *(const float4*)(dp + 4);
    *(float4*)&wfv[0] = *(const float4*)(wf + lane * 8);
    *(float4*)&wfv[4] = *(const float4*)(wf + lane * 8 + 4);
  }
  float bfv = bfp[0];
  for (int p = wid; p < P_; p += 16){
    short8 e = *(const short8*)(enc_att + ((size_t)b * P_ + p) * A_ + lane * 8);
    float s = 0.f;
#pragma unroll
    for (int j = 0; j < 8; j++){
      float v = bf2f((unsigned short)e[j]) + dav[j];
      s += fmaxf(v, 0.f) * wfv[j];
    }
#pragma unroll
    for (int off = 32; off > 0; off >>= 1) s += __shfl_down(s, off);
    if (lane == 0) sc[p] = s + bfv;
  }
  __syncthreads();

  // ---- phase 2: softmax over 196 ----
  if (tid < 256) red[tid] = (tid < P_) ? sc[tid] : -1e30f;
  __syncthreads();
  for (int s = 128; s > 0; s >>= 1){ if (tid < s) red[tid] = fmaxf(red[tid], red[tid + s]); __syncthreads(); }
  float mx = red[0];
  __syncthreads();
  float ex = 0.f;
  if (tid < 256){ ex = (tid < P_) ? expf(sc[tid] - mx) : 0.f; red[tid] = ex; }
  __syncthreads();
  for (int s = 128; s > 0; s >>= 1){ if (tid < s) red[tid] += red[tid + s]; __syncthreads(); }
  float inv = 1.f / red[0];
  if (tid < P_) al[tid] = ex * inv;
  __syncthreads();

  // ---- phase 3: awe with 4-way p split ----
  int pg = tid >> 8, et = tid & 255;
  int e0 = bx * 1024 + et * 4;
  const unsigned short* encb = enc_s + (size_t)b * (P_ * ENC_) + e0;
  float a0 = 0.f, a1 = 0.f, a2 = 0.f, a3 = 0.f;
  int pbeg = pg * 49;
#pragma unroll 7
  for (int p = pbeg; p < pbeg + 49; p++){
    float a = al[p];
    short4v v = *(const short4v*)(encb + (size_t)p * ENC_);
    a0 += a * bf2f((unsigned short)v[0]);
    a1 += a * bf2f((unsigned short)v[1]);
    a2 += a * bf2f((unsigned short)v[2]);
    a3 += a * bf2f((unsigned short)v[3]);
  }
  float4 pv; pv.x = a0; pv.y = a1; pv.z = a2; pv.w = a3;
  part[pg][et] = pv;
  __syncthreads();
  if (pg == 0){
    float4 s0 = part[0][et], s1 = part[1][et], s2 = part[2][et], s3 = part[3][et];
    float4 g4 = *(const float4*)(out_pre + (size_t)b * 2560 + 512 + e0);
    short4v r;
    r[0] = (short)f2bf(sigf(g4.x) * (s0.x + s1.x + s2.x + s3.x));
    r[1] = (short)f2bf(sigf(g4.y) * (s0.y + s1.y + s2.y + s3.y));
    r[2] = (short)f2bf(sigf(g4.z) * (s0.z + s1.z + s2.z + s3.z));
    r[3] = (short)f2bf(sigf(g4.w) * (s0.w + s1.w + s2.w + s3.w));
    *(short4v*)(xh + (size_t)b * 3072 + 512 + e0) = r;
  }
  if (bx == 1 && tid < 512){
    int tok = caps_sorted[b * L_ + t];
    xh[(size_t)b * 3072 + tid] = f2bf(emb[(size_t)tok * E_ + tid]);
  }
  // copy h (bf16) into xh K-range [2560,3072) for this step's gates GEMM
  if (bx == 0 && tid < 512)
    xh[(size_t)b * 3072 + 2560 + tid] = h_b[(size_t)b * 512 + tid];
}

// ---------------- gates GEMM (split-K=4, atomic) + last-slice LSTM finisher --
// gates[b][cc] gate-interleaved. Tile n covers complete (i,f,g,o) for d in
// [tile*32, tile*32+32). Last-arriving slice runs the LSTM for that d-range.
__launch_bounds__(256)
__global__ void gemm_gates_fused(const unsigned short* __restrict__ Axh,
                                 const unsigned short* __restrict__ Bm,
                                 float* __restrict__ gates,
                                 int* __restrict__ cnt,
                                 float* __restrict__ h, float* __restrict__ c,
                                 unsigned short* __restrict__ h_b,
                                 unsigned short* __restrict__ hnew_b,
                                 const float* __restrict__ bias_pre,
                                 float* __restrict__ out_pre,
                                 const int* __restrict__ dec_len, int t){
  __shared__ unsigned short As[128 * 32];
  __shared__ unsigned short Bs[128 * 32];
  __shared__ int ticket_s;
  int m0 = 0, n0 = blockIdx.x * 128;
  int kb = blockIdx.z * 768;
  const unsigned short* Ap = Axh + kb;
  const unsigned short* Bp = Bm + kb;
  GEMM_CORE(Ap, 3072, Bp, 3072, 768, 2047)
#pragma unroll
  for (int mi = 0; mi < 4; mi++)
#pragma unroll
    for (int ni = 0; ni < 4; ni++){
      int col = n0 + nbase + ni * 16 + fr;
      int rb = mbase + mi * 16 + ((lane >> 4) << 2);
#pragma unroll
      for (int r = 0; r < 4; r++)
        atomicAdd(&gates[(size_t)(rb + r) * 2048 + col], acc[mi][ni][r]);
    }
  __threadfence();
  __syncthreads();
  if (tid == 0) ticket_s = atomicAdd(&cnt[blockIdx.x], 1);
  __syncthreads();
  if (ticket_s != 3) return;
  __threadfence();
  int tile = blockIdx.x;
  // LSTM for d in [tile*32, tile*32+32), all 128 b
  for (int e = tid; e < 128 * 32; e += 256){
    int b = e >> 5, dl = e & 31;
    int d = tile * 32 + dl;
    int base = b * 2048 + tile * 128 + ((dl >> 4) << 6) + (dl & 15);
    float iv = gates[base];
    float fv = gates[base + 16];
    float gv = gates[base + 32];
    float ov = gates[base + 48];
    int idx = b * 512 + d;
    float cold = c[idx];
    float cn = sigf(fv) * cold + sigf(iv) * tanhf(gv);
    float hn = sigf(ov) * tanhf(cn);
    bool act = t < dec_len[b];
    float hv = act ? hn : h[idx];
    float cv = act ? cn : cold;
    h[idx] = hv; c[idx] = cv;
    h_b[idx] = f2bf(hv);
    hnew_b[(size_t)t * (B_ * D_) + idx] = f2bf(hn);
  }
  // re-init this tile's out_pre slice (cols [tile*160, tile*160+160)) for next step
  for (int e = tid; e < 128 * 160; e += 256){
    int b = e / 160, col = tile * 160 + (e - (e / 160) * 160);
    out_pre[(size_t)b * 2560 + col] = bias_pre[col];
  }
}

// ---------------- preds GEMM: XCD-rect partition + LDS-staged stores ---------
// virtual grid 52m x 80n tiles over 8 XCDs (4 m-chunks x 2 n-chunks), m-fastest.
__launch_bounds__(256)
__global__ void gemm_preds(const unsigned short* __restrict__ A,    // hnew_b 6528x512
                           const unsigned short* __restrict__ Bm,   // Wfc_b 10000x512
                           const float* __restrict__ bias,
                           float* __restrict__ Cf,
                           const int* __restrict__ dec_len){
  __shared__ __attribute__((aligned(16))) char smem[4 * 64 * 68 * 4];
  unsigned short* As = (unsigned short*)smem;
  unsigned short* Bs = (unsigned short*)(smem + 8192);
  int bid = blockIdx.x;
  int xcd = bid & 7, i = bid >> 3;          // i in [0,520)
  int mchunk = xcd >> 1, nchunk = xcd & 1;
  int mi_ = i % 13, ni_ = i / 13;
  int mt = mchunk * 13 + mi_;
  int nt = nchunk * 40 + ni_;
  if (mt >= 51 || nt >= 79) return;
  int m0 = mt * 128, n0 = nt * 128;
  GEMM_CORE(A, D_, Bm, D_, D_, V_ - 1)
  float* Cs = (float*)smem + (size_t)w * (64 * 68);
#pragma unroll
  for (int mi = 0; mi < 4; mi++)
#pragma unroll
    for (int ni = 0; ni < 4; ni++){
      int lc = ni * 16 + fr;
      int col = n0 + nbase + lc;
      float bb = bias[col < V_ ? col : V_ - 1];
#pragma unroll
      for (int r = 0; r < 4; r++){
        int lr = mi * 16 + ((lane >> 4) << 2) + r;
        Cs[lr * 68 + lc] = acc[mi][ni][r] + bb;
      }
    }
#pragma unroll
  for (int rd = 0; rd < 16; rd++){
    int lr = rd * 4 + (lane >> 4);
    int m = m0 + mbase + lr;
    int tt = m >> 7, b = m & 127;
    int col = n0 + nbase + fr * 4;
    floatx4 v = *(const floatx4*)&Cs[lr * 68 + fr * 4];
    if (tt >= dec_len[b]){ v[0] = 0.f; v[1] = 0.f; v[2] = 0.f; v[3] = 0.f; }
    if (col < V_)
      __builtin_nontemporal_store(v, (floatx4*)(Cf + ((size_t)b * T_ + tt) * V_ + col));
  }
}

extern "C" void kernel_launch(void* const* d_in, const int* in_sizes, int n_in,
                              void* d_out, int out_size, void* d_ws, size_t ws_size,
                              hipStream_t stream) {
  const float* encoder_out = (const float*)d_in[0];
  const int*   caps        = (const int*)d_in[1];
  const int*   cap_len     = (const int*)d_in[2];
  const float* emb         = (const float*)d_in[3];
  const float* We          = (const float*)d_in[4];
  const float* be          = (const float*)d_in[5];
  const float* Wd          = (const float*)d_in[6];
  const float* bd          = (const float*)d_in[7];
  const float* wf          = (const float*)d_in[8];
  const float* bf          = (const float*)d_in[9];
  const float* W_ih        = (const float*)d_in[10];
  const float* b_ih        = (const float*)d_in[11];
  const float* W_hh        = (const float*)d_in[12];
  const float* b_hh        = (const float*)d_in[13];
  const float* Wbeta       = (const float*)d_in[14];
  const float* bbeta       = (const float*)d_in[15];
  const float* Wfc         = (const float*)d_in[16];
  const float* bfc         = (const float*)d_in[17];

  float* out_preds  = (float*)d_out;
  float* out_caps   = out_preds + (size_t)B_ * T_ * V_;
  float* out_declen = out_caps + (size_t)B_ * L_;

  char* w = (char*)d_ws;
  auto alloc = [&](size_t bytes) -> void* {
    void* p = (void*)w;
    w += (bytes + 255) & ~(size_t)255;
    return p;
  };
  int*   order       = (int*)alloc(B_ * 4);
  int*   dec_len     = (int*)alloc(B_ * 4);
  int*   caps_sorted = (int*)alloc((size_t)B_ * L_ * 4);
  unsigned short* enc_s   = (unsigned short*)alloc((size_t)B_ * P_ * ENC_ * 2);
  unsigned short* We_b    = (unsigned short*)alloc((size_t)512 * 2048 * 2);
  unsigned short* Wpre_b  = (unsigned short*)alloc((size_t)2560 * 512 * 2);
  unsigned short* Wg_b    = (unsigned short*)alloc((size_t)2048 * 3072 * 2);
  unsigned short* Wfc_b   = (unsigned short*)alloc((size_t)10000 * 512 * 2);
  unsigned short* enc_att = (unsigned short*)alloc((size_t)B_ * P_ * A_ * 2);
  float* bias_pre    = (float*)alloc(2560 * 4);
  float* bias_g      = (float*)alloc(2048 * 4);
  float* out_pre     = (float*)alloc((size_t)B_ * 2560 * 4);
  unsigned short* xh = (unsigned short*)alloc((size_t)B_ * 3072 * 2);
  float* gates       = (float*)alloc((size_t)B_ * 2048 * 4);
  float* h           = (float*)alloc((size_t)B_ * D_ * 4);
  float* c           = (float*)alloc((size_t)B_ * D_ * 4);
  unsigned short* h_b = (unsigned short*)alloc((size_t)B_ * D_ * 2);
  unsigned short* hnew_b = (unsigned short*)alloc((size_t)T_ * B_ * D_ * 2);
  int* cnt           = (int*)alloc(64);

  sort_kernel<<<1, 128, 0, stream>>>(cap_len, caps, order, dec_len, caps_sorted, out_caps, out_declen);
  gather_kernel<<<dim3(392, 128), 256, 0, stream>>>(encoder_out, order, enc_s);
  prep_kernel<<<2048, 256, 0, stream>>>(We, Wd, Wbeta, W_ih, W_hh, Wfc, bd, bbeta, b_ih, b_hh,
                                        We_b, Wpre_b, Wg_b, Wfc_b, bias_pre, bias_g,
                                        out_pre, h, c, h_b, xh, cnt);

  // enc_att = enc_s @ We^T + be -> bf16 : M=25088, N=512, K=2048
  gemm_bf16<<<dim3(4, 196, 1), 256, 0, stream>>>(
      enc_s, ENC_, We_b, ENC_, be, nullptr, enc_att, A_, A_, ENC_, 1);

  for (int t = 0; t < T_; t++){
    // out_pre += h @ [Wd;Wbeta]^T  (split-K=4, bias pre-initialized)
    gemm_bf16<<<dim3(20, 1, 4), 256, 0, stream>>>(
        h_b, D_, Wpre_b, D_, nullptr, out_pre, nullptr, 2560, 2560, 128, 0);

    // attention -> xh = [emb | gate*awe | h]; init gates=bias_g; zero cnt
    attn_kernel<<<dim3(2, B_), 1024, 0, stream>>>(enc_att, enc_s, out_pre, wf, bf,
                                                  emb, caps_sorted, h_b, xh, gates, bias_g, cnt, t);

    // gates += xh @ Wg^T (split-K=4, atomic) + last-slice LSTM finisher
    gemm_gates_fused<<<dim3(16, 1, 4), 256, 0, stream>>>(xh, Wg_b, gates, cnt,
                                                         h, c, h_b, hnew_b,
                                                         bias_pre, out_pre, dec_len, t);
  }

  // preds: (T*B, V) = hnew @ Wfc^T + bfc, masked + scattered to (B,T,V)
  gemm_preds<<<4160, 256, 0, stream>>>(hnew_b, Wfc_b, bfc, out_preds, dec_len);
}

// Round 6
// 3895.659 us; speedup vs baseline: 3.9609x; 1.2160x over previous
//
#include <hip/hip_runtime.h>
#include <cstdint>
#include <cstddef>

#define B_ 128
#define P_ 196
#define ENC_ 2048
#define A_ 512
#define E_ 512
#define D_ 512
#define V_ 10000
#define L_ 52
#define T_ 51

using short8 = __attribute__((ext_vector_type(8))) short;
using short4v = __attribute__((ext_vector_type(4))) short;
using floatx4 = __attribute__((ext_vector_type(4))) float;

__device__ __forceinline__ float sigf(float x){ return 1.f/(1.f+expf(-x)); }

__device__ __forceinline__ unsigned short f2bf(float f){
  unsigned int u = __float_as_uint(f);
  unsigned int r = (u + 0x7fffu + ((u >> 16) & 1u)) >> 16;
  return (unsigned short)r;
}
__device__ __forceinline__ float bf2f(unsigned short u){
  return __uint_as_float(((unsigned int)u) << 16);
}

// ---------------- sort (stable descending by length) ----------------
__global__ void sort_kernel(const int* __restrict__ cap_len, const int* __restrict__ caps,
                            int* __restrict__ order, int* __restrict__ dec_len,
                            int* __restrict__ caps_sorted,
                            float* __restrict__ out_caps, float* __restrict__ out_declen){
  __shared__ int len_s[B_];
  int i = threadIdx.x;
  len_s[i] = cap_len[i];
  __syncthreads();
  int li = len_s[i];
  int pos = 0;
  for (int j = 0; j < B_; j++){
    int lj = len_s[j];
    pos += (lj > li) || (lj == li && j < i);
  }
  order[pos] = i;
  dec_len[pos] = li - 1;
  out_declen[pos] = (float)(li - 1);
  for (int l = 0; l < L_; l++){
    int v = caps[i * L_ + l];
    caps_sorted[pos * L_ + l] = v;
    out_caps[pos * L_ + l] = (float)v;
  }
}

// ---------------- enc gather + fp32->bf16 ----------------
__global__ void gather_kernel(const float* __restrict__ enc, const int* __restrict__ order,
                              unsigned short* __restrict__ enc_s){
  int b = blockIdx.y;
  int i = (blockIdx.x * 256 + threadIdx.x) * 4;
  const float4 v = *(const float4*)(enc + (size_t)order[b] * (P_ * ENC_) + i);
  short4v r;
  r[0] = (short)f2bf(v.x); r[1] = (short)f2bf(v.y);
  r[2] = (short)f2bf(v.z); r[3] = (short)f2bf(v.w);
  *(short4v*)(enc_s + (size_t)b * (P_ * ENC_) + i) = r;
}

// ---------------- weight conversion/packing + state init ----------------
__global__ void prep_kernel(const float* __restrict__ We, const float* __restrict__ Wd,
                            const float* __restrict__ Wbeta,
                            const float* __restrict__ W_ih, const float* __restrict__ W_hh,
                            const float* __restrict__ Wfc,
                            const float* __restrict__ bd, const float* __restrict__ bbeta,
                            const float* __restrict__ b_ih, const float* __restrict__ b_hh,
                            unsigned short* __restrict__ We_b, unsigned short* __restrict__ Wpre_b,
                            unsigned short* __restrict__ Wg_b, unsigned short* __restrict__ Wfc_b,
                            float* __restrict__ bias_pre, float* __restrict__ bias_g,
                            float* __restrict__ out_pre,
                            float* __restrict__ h, float* __restrict__ c,
                            unsigned short* __restrict__ h_b, unsigned short* __restrict__ xh){
  unsigned int idx = blockIdx.x * blockDim.x + threadIdx.x;
  unsigned int stride = gridDim.x * blockDim.x;
  // We_b: 512x2048 direct
  for (unsigned int i = idx; i < 512u * 2048u; i += stride) We_b[i] = f2bf(We[i]);
  // Wpre_b = [Wd(512x512) ; Wbeta(2048x512)] flat concat (K matches)
  for (unsigned int i = idx; i < 2560u * 512u; i += stride)
    Wpre_b[i] = f2bf(i < 512u * 512u ? Wd[i] : Wbeta[i - 512u * 512u]);
  // Wg_b rows: [W_ih row(2560) | W_hh row(512)] -> 2048 x 3072
  for (unsigned int i = idx; i < 2048u * 3072u; i += stride){
    unsigned int j = i / 3072u, k = i - j * 3072u;
    Wg_b[i] = f2bf(k < 2560u ? W_ih[j * 2560u + k] : W_hh[j * 512u + (k - 2560u)]);
  }
  // Wfc_b: 10000x512 direct
  for (unsigned int i = idx; i < 10000u * 512u; i += stride) Wfc_b[i] = f2bf(Wfc[i]);
  // biases
  for (unsigned int i = idx; i < 2560u; i += stride) bias_pre[i] = (i < 512u) ? bd[i] : bbeta[i - 512u];
  for (unsigned int i = idx; i < 2048u; i += stride) bias_g[i] = b_ih[i] + b_hh[i];
  // out_pre init (t=0) = bias broadcast
  for (unsigned int i = idx; i < (unsigned)B_ * 2560u; i += stride){
    unsigned int k = i % 2560u;
    out_pre[i] = (k < 512u) ? bd[k] : bbeta[k - 512u];
  }
  // state init
  for (unsigned int i = idx; i < (unsigned)B_ * D_; i += stride){
    h[i] = 0.f; c[i] = 0.f; h_b[i] = 0;
    unsigned int b = i >> 9, d = i & 511u;
    xh[(size_t)b * 3072 + 2560 + d] = 0;
  }
}

// ---------------- 256-thread GEMM core: C(128x128) = A(MxK) @ B(NxK)^T -------
#define GEMM_CORE(Aptr, LDA, Bptr, LDB, KDIM, NCLAMP)                         \
  int tid = threadIdx.x; int lane = tid & 63; int w = tid >> 6;               \
  const floatx4 vzero = {0.f,0.f,0.f,0.f};                                    \
  floatx4 acc[4][4];                                                          \
  _Pragma("unroll") for (int i_=0;i_<4;i_++)                                  \
  _Pragma("unroll") for (int j_=0;j_<4;j_++) acc[i_][j_]=vzero;               \
  int mbase=(w&1)<<6, nbase=(w>>1)<<6;                                        \
  int fr=lane&15, fk=(lane>>4)<<3;                                            \
  for (int k0=0;k0<(KDIM);k0+=32){                                            \
    _Pragma("unroll") for (int r_=0;r_<2;r_++){                               \
      int chunk=r_*256+tid; int row=chunk>>2, kc=(chunk&3)<<3;                \
      short8 av=*(const short8*)((Aptr)+(size_t)(m0+row)*(LDA)+k0+kc);        \
      int bn=n0+row; if(bn>(NCLAMP)) bn=(NCLAMP);                             \
      short8 bv=*(const short8*)((Bptr)+(size_t)bn*(LDB)+k0+kc);              \
      *(short8*)&As[chunk*8]=av; *(short8*)&Bs[chunk*8]=bv; }                 \
    __syncthreads();                                                          \
    short8 af[4], bfrag[4];                                                   \
    _Pragma("unroll") for (int i_=0;i_<4;i_++){                               \
      af[i_]=*(const short8*)&As[(mbase+i_*16+fr)*32+fk];                     \
      bfrag[i_]=*(const short8*)&Bs[(nbase+i_*16+fr)*32+fk]; }                \
    _Pragma("unroll") for (int mi_=0;mi_<4;mi_++)                             \
    _Pragma("unroll") for (int ni_=0;ni_<4;ni_++)                             \
      acc[mi_][ni_]=__builtin_amdgcn_mfma_f32_16x16x32_bf16(af[mi_],bfrag[ni_],acc[mi_][ni_],0,0,0); \
    __syncthreads(); }

// ---------------- generic GEMM (epi 0: atomic fp32; epi 1: bf16 + bias) ------
__launch_bounds__(256)
__global__ void gemm_bf16(const unsigned short* __restrict__ A, int lda,
                          const unsigned short* __restrict__ Bm, int ldb,
                          const float* __restrict__ bias,
                          float* __restrict__ Cf, unsigned short* __restrict__ Cb, int ldc,
                          int N, int ksz, int epi)
{
  __shared__ unsigned short As[128 * 32];
  __shared__ unsigned short Bs[128 * 32];
  int m0 = blockIdx.y * 128, n0 = blockIdx.x * 128;
  int kb = blockIdx.z * ksz;
  const unsigned short* Ap = A + kb;
  const unsigned short* Bp = Bm + kb;
  GEMM_CORE(Ap, lda, Bp, ldb, ksz, N - 1)
#pragma unroll
  for (int mi = 0; mi < 4; mi++)
#pragma unroll
    for (int ni = 0; ni < 4; ni++){
      floatx4 v = acc[mi][ni];
      int col = n0 + nbase + ni * 16 + fr;
      int rb = m0 + mbase + mi * 16 + ((lane >> 4) << 2);
      if (epi == 0){
#pragma unroll
        for (int r = 0; r < 4; r++)
          atomicAdd(&Cf[(size_t)(rb + r) * ldc + col], v[r]);
      } else {
        float bb = bias[col];
#pragma unroll
        for (int r = 0; r < 4; r++)
          Cb[(size_t)(rb + r) * ldc + col] = f2bf(v[r] + bb);
      }
    }
}

// ---------------- fused attention: scores + softmax + awe + gate -> xh ------
// grid (2, 128) x 1024 threads; also inits gates = bias_g for this step.
__launch_bounds__(1024)
__global__ void attn_kernel(const unsigned short* __restrict__ enc_att,
                            const unsigned short* __restrict__ enc_s,
                            const float* __restrict__ out_pre,
                            const float* __restrict__ wf, const float* __restrict__ bfp,
                            const float* __restrict__ emb, const int* __restrict__ caps_sorted,
                            unsigned short* __restrict__ xh,
                            float* __restrict__ gates, const float* __restrict__ bias_g,
                            int t){
  __shared__ float sc[P_];
  __shared__ float al[P_];
  __shared__ float red[256];
  __shared__ float part2[8][128][8];   // 32 KB: 8 p-groups x 128 e-threads x 8 elems
  int b = blockIdx.y, bx = blockIdx.x, tid = threadIdx.x;

  // init gates buffer for this step's split-K GEMM (previous lstm finished reading it)
  int gid = (b * 2 + bx) * 1024 + tid;   // covers exactly B_*2048
  gates[gid] = bias_g[gid & 2047];

  // ---- phase 1: scores ----
  int wid = tid >> 6, lane = tid & 63;
  float dav[8], wfv[8];
  {
    const float* dp = out_pre + (size_t)b * 2560 + lane * 8;
    *(float4*)&dav[0] = *(const float4*)(dp);
    *(float4*)&dav[4] = *(const float4*)(dp + 4);
    *(float4*)&wfv[0] = *(const float4*)(wf + lane * 8);
    *(float4*)&wfv[4] = *(const float4*)(wf + lane * 8 + 4);
  }
  float bfv = bfp[0];
  for (int p = wid; p < P_; p += 16){
    short8 e = *(const short8*)(enc_att + ((size_t)b * P_ + p) * A_ + lane * 8);
    float s = 0.f;
#pragma unroll
    for (int j = 0; j < 8; j++){
      float v = bf2f((unsigned short)e[j]) + dav[j];
      s += fmaxf(v, 0.f) * wfv[j];
    }
#pragma unroll
    for (int off = 32; off > 0; off >>= 1) s += __shfl_down(s, off);
    if (lane == 0) sc[p] = s + bfv;
  }
  __syncthreads();

  // ---- phase 2: softmax over 196 ----
  if (tid < 256) red[tid] = (tid < P_) ? sc[tid] : -1e30f;
  __syncthreads();
  for (int s = 128; s > 0; s >>= 1){ if (tid < s) red[tid] = fmaxf(red[tid], red[tid + s]); __syncthreads(); }
  float mx = red[0];
  __syncthreads();
  float ex = 0.f;
  if (tid < 256){ ex = (tid < P_) ? expf(sc[tid] - mx) : 0.f; red[tid] = ex; }
  __syncthreads();
  for (int s = 128; s > 0; s >>= 1){ if (tid < s) red[tid] += red[tid + s]; __syncthreads(); }
  float inv = 1.f / red[0];
  if (tid < P_) al[tid] = ex * inv;
  __syncthreads();

  // ---- phase 3: awe with 8-way p split, 16B loads ----
  int pg = tid >> 7, et = tid & 127;
  int e0 = bx * 1024 + et * 8;
  const unsigned short* encb = enc_s + (size_t)b * (P_ * ENC_) + e0;
  float aa[8];
#pragma unroll
  for (int j = 0; j < 8; j++) aa[j] = 0.f;
  int pbeg = (pg * 196) >> 3, pend = ((pg + 1) * 196) >> 3;
#pragma unroll 5
  for (int p = pbeg; p < pend; p++){
    float a = al[p];
    short8 v = *(const short8*)(encb + (size_t)p * ENC_);
#pragma unroll
    for (int j = 0; j < 8; j++)
      aa[j] += a * bf2f((unsigned short)v[j]);
  }
#pragma unroll
  for (int j = 0; j < 8; j++) part2[pg][et][j] = aa[j];
  __syncthreads();
  if (pg == 0){
    float s[8];
#pragma unroll
    for (int j = 0; j < 8; j++){
      float acc = 0.f;
#pragma unroll
      for (int g = 0; g < 8; g++) acc += part2[g][et][j];
      s[j] = acc;
    }
    const float* gp = out_pre + (size_t)b * 2560 + 512 + e0;
    short8 r;
#pragma unroll
    for (int j = 0; j < 8; j++)
      r[j] = (short)f2bf(sigf(gp[j]) * s[j]);
    *(short8*)(xh + (size_t)b * 3072 + 512 + e0) = r;
  }
  // emb gather for this step's token into xh[:512]
  if (bx == 1 && tid < 512){
    int tok = caps_sorted[b * L_ + t];
    xh[(size_t)b * 3072 + tid] = f2bf(emb[(size_t)tok * E_ + tid]);
  }
}

// ---------------- LSTM pointwise; init out_pre=bias for next step ----------------
__global__ void lstm_kernel(const float* __restrict__ gates, float* __restrict__ h, float* __restrict__ c,
                            unsigned short* __restrict__ h_b, unsigned short* __restrict__ xh,
                            unsigned short* __restrict__ hnew_b,
                            float* __restrict__ out_pre, const float* __restrict__ bias_pre,
                            const int* __restrict__ dec_len, int t){
  int idx = blockIdx.x * 256 + threadIdx.x;   // 65536 total
  int b = idx >> 9, d = idx & 511;
  const float* gr = gates + (size_t)b * 2048;
  float i_ = gr[d], f_ = gr[512 + d], g_ = gr[1024 + d], o_ = gr[1536 + d];
  float cn = sigf(f_) * c[idx] + sigf(i_) * tanhf(g_);
  float hn = sigf(o_) * tanhf(cn);
  bool act = t < dec_len[b];
  float hv = act ? hn : h[idx];
  float cv = act ? cn : c[idx];
  h[idx] = hv; c[idx] = cv;
  unsigned short hvb = f2bf(hv);
  h_b[idx] = hvb;
  xh[(size_t)b * 3072 + 2560 + d] = hvb;
  hnew_b[(size_t)t * (B_ * D_) + idx] = f2bf(hn);
  for (int j = idx; j < B_ * 2560; j += B_ * D_) out_pre[j] = bias_pre[j % 2560];
}

// ---------------- preds GEMM: XCD-rect partition + LDS-staged stores ---------
// virtual grid 52m x 80n tiles over 8 XCDs (4 m-chunks x 2 n-chunks), m-fastest.
__launch_bounds__(256)
__global__ void gemm_preds(const unsigned short* __restrict__ A,    // hnew_b 6528x512
                           const unsigned short* __restrict__ Bm,   // Wfc_b 10000x512
                           const float* __restrict__ bias,
                           float* __restrict__ Cf,
                           const int* __restrict__ dec_len){
  __shared__ __attribute__((aligned(16))) char smem[4 * 64 * 68 * 4];
  unsigned short* As = (unsigned short*)smem;
  unsigned short* Bs = (unsigned short*)(smem + 8192);
  int bid = blockIdx.x;
  int xcd = bid & 7, i = bid >> 3;          // i in [0,520)
  int mchunk = xcd >> 1, nchunk = xcd & 1;
  int mi_ = i % 13, ni_ = i / 13;
  int mt = mchunk * 13 + mi_;
  int nt = nchunk * 40 + ni_;
  if (mt >= 51 || nt >= 79) return;
  int m0 = mt * 128, n0 = nt * 128;
  GEMM_CORE(A, D_, Bm, D_, D_, V_ - 1)
  float* Cs = (float*)smem + (size_t)w * (64 * 68);
#pragma unroll
  for (int mi = 0; mi < 4; mi++)
#pragma unroll
    for (int ni = 0; ni < 4; ni++){
      int lc = ni * 16 + fr;
      int col = n0 + nbase + lc;
      float bb = bias[col < V_ ? col : V_ - 1];
#pragma unroll
      for (int r = 0; r < 4; r++){
        int lr = mi * 16 + ((lane >> 4) << 2) + r;
        Cs[lr * 68 + lc] = acc[mi][ni][r] + bb;
      }
    }
#pragma unroll
  for (int rd = 0; rd < 16; rd++){
    int lr = rd * 4 + (lane >> 4);
    int m = m0 + mbase + lr;
    int tt = m >> 7, b = m & 127;
    int col = n0 + nbase + fr * 4;
    floatx4 v = *(const floatx4*)&Cs[lr * 68 + fr * 4];
    if (tt >= dec_len[b]){ v[0] = 0.f; v[1] = 0.f; v[2] = 0.f; v[3] = 0.f; }
    if (col < V_)
      __builtin_nontemporal_store(v, (floatx4*)(Cf + ((size_t)b * T_ + tt) * V_ + col));
  }
}

extern "C" void kernel_launch(void* const* d_in, const int* in_sizes, int n_in,
                              void* d_out, int out_size, void* d_ws, size_t ws_size,
                              hipStream_t stream) {
  const float* encoder_out = (const float*)d_in[0];
  const int*   caps        = (const int*)d_in[1];
  const int*   cap_len     = (const int*)d_in[2];
  const float* emb         = (const float*)d_in[3];
  const float* We          = (const float*)d_in[4];
  const float* be          = (const float*)d_in[5];
  const float* Wd          = (const float*)d_in[6];
  const float* bd          = (const float*)d_in[7];
  const float* wf          = (const float*)d_in[8];
  const float* bf          = (const float*)d_in[9];
  const float* W_ih        = (const float*)d_in[10];
  const float* b_ih        = (const float*)d_in[11];
  const float* W_hh        = (const float*)d_in[12];
  const float* b_hh        = (const float*)d_in[13];
  const float* Wbeta       = (const float*)d_in[14];
  const float* bbeta       = (const float*)d_in[15];
  const float* Wfc         = (const float*)d_in[16];
  const float* bfc         = (const float*)d_in[17];

  float* out_preds  = (float*)d_out;
  float* out_caps   = out_preds + (size_t)B_ * T_ * V_;
  float* out_declen = out_caps + (size_t)B_ * L_;

  char* w = (char*)d_ws;
  auto alloc = [&](size_t bytes) -> void* {
    void* p = (void*)w;
    w += (bytes + 255) & ~(size_t)255;
    return p;
  };
  int*   order       = (int*)alloc(B_ * 4);
  int*   dec_len     = (int*)alloc(B_ * 4);
  int*   caps_sorted = (int*)alloc((size_t)B_ * L_ * 4);
  unsigned short* enc_s   = (unsigned short*)alloc((size_t)B_ * P_ * ENC_ * 2);
  unsigned short* We_b    = (unsigned short*)alloc((size_t)512 * 2048 * 2);
  unsigned short* Wpre_b  = (unsigned short*)alloc((size_t)2560 * 512 * 2);
  unsigned short* Wg_b    = (unsigned short*)alloc((size_t)2048 * 3072 * 2);
  unsigned short* Wfc_b   = (unsigned short*)alloc((size_t)10000 * 512 * 2);
  unsigned short* enc_att = (unsigned short*)alloc((size_t)B_ * P_ * A_ * 2);
  float* bias_pre    = (float*)alloc(2560 * 4);
  float* bias_g      = (float*)alloc(2048 * 4);
  float* out_pre     = (float*)alloc((size_t)B_ * 2560 * 4);
  unsigned short* xh = (unsigned short*)alloc((size_t)B_ * 3072 * 2);
  float* gates       = (float*)alloc((size_t)B_ * 2048 * 4);
  float* h           = (float*)alloc((size_t)B_ * D_ * 4);
  float* c           = (float*)alloc((size_t)B_ * D_ * 4);
  unsigned short* h_b = (unsigned short*)alloc((size_t)B_ * D_ * 2);
  unsigned short* hnew_b = (unsigned short*)alloc((size_t)T_ * B_ * D_ * 2);

  sort_kernel<<<1, 128, 0, stream>>>(cap_len, caps, order, dec_len, caps_sorted, out_caps, out_declen);
  gather_kernel<<<dim3(392, 128), 256, 0, stream>>>(encoder_out, order, enc_s);
  prep_kernel<<<2048, 256, 0, stream>>>(We, Wd, Wbeta, W_ih, W_hh, Wfc, bd, bbeta, b_ih, b_hh,
                                        We_b, Wpre_b, Wg_b, Wfc_b, bias_pre, bias_g,
                                        out_pre, h, c, h_b, xh);

  // enc_att = enc_s @ We^T + be -> bf16 : M=25088, N=512, K=2048
  gemm_bf16<<<dim3(4, 196, 1), 256, 0, stream>>>(
      enc_s, ENC_, We_b, ENC_, be, nullptr, enc_att, A_, A_, ENC_, 1);

  for (int t = 0; t < T_; t++){
    // out_pre += h @ [Wd;Wbeta]^T  (split-K=4, bias pre-initialized)
    gemm_bf16<<<dim3(20, 1, 4), 256, 0, stream>>>(
        h_b, D_, Wpre_b, D_, nullptr, out_pre, nullptr, 2560, 2560, 128, 0);

    // attention -> xh = [emb | gate*awe]; init gates = bias_g
    attn_kernel<<<dim3(2, B_), 1024, 0, stream>>>(enc_att, enc_s, out_pre, wf, bf,
                                                  emb, caps_sorted, xh, gates, bias_g, t);

    // gates += xh @ [W_ih|W_hh]^T  (split-K=4, atomic)
    gemm_bf16<<<dim3(16, 1, 4), 256, 0, stream>>>(
        xh, 3072, Wg_b, 3072, nullptr, gates, nullptr, 2048, 2048, 768, 0);

    lstm_kernel<<<(B_ * D_) / 256, 256, 0, stream>>>(gates, h, c, h_b, xh, hnew_b,
                                                     out_pre, bias_pre, dec_len, t);
  }

  // preds: (T*B, V) = hnew @ Wfc^T + bfc, masked + scattered to (B,T,V)
  gemm_preds<<<4160, 256, 0, stream>>>(hnew_b, Wfc_b, bfc, out_preds, dec_len);
}

// Round 7
// 3789.800 us; speedup vs baseline: 4.0715x; 1.0279x over previous
//
#include <hip/hip_runtime.h>
#include <cstdint>
#include <cstddef>

#define B_ 128
#define P_ 196
#define ENC_ 2048
#define A_ 512
#define E_ 512
#define D_ 512
#define V_ 10000
#define L_ 52
#define T_ 51

using short8 = __attribute__((ext_vector_type(8))) short;
using short4v = __attribute__((ext_vector_type(4))) short;
using floatx4 = __attribute__((ext_vector_type(4))) float;

__device__ __forceinline__ float sigf(float x){ return 1.f/(1.f+expf(-x)); }

__device__ __forceinline__ unsigned short f2bf(float f){
  unsigned int u = __float_as_uint(f);
  unsigned int r = (u + 0x7fffu + ((u >> 16) & 1u)) >> 16;
  return (unsigned short)r;
}
__device__ __forceinline__ float bf2f(unsigned short u){
  return __uint_as_float(((unsigned int)u) << 16);
}

// ---------------- sort (stable descending by length) ----------------
__global__ void sort_kernel(const int* __restrict__ cap_len, const int* __restrict__ caps,
                            int* __restrict__ order, int* __restrict__ dec_len,
                            int* __restrict__ caps_sorted,
                            float* __restrict__ out_caps, float* __restrict__ out_declen){
  __shared__ int len_s[B_];
  int i = threadIdx.x;
  len_s[i] = cap_len[i];
  __syncthreads();
  int li = len_s[i];
  int pos = 0;
  for (int j = 0; j < B_; j++){
    int lj = len_s[j];
    pos += (lj > li) || (lj == li && j < i);
  }
  order[pos] = i;
  dec_len[pos] = li - 1;
  out_declen[pos] = (float)(li - 1);
  for (int l = 0; l < L_; l++){
    int v = caps[i * L_ + l];
    caps_sorted[pos * L_ + l] = v;
    out_caps[pos * L_ + l] = (float)v;
  }
}

// ---------------- enc gather + fp32->bf16 ----------------
__global__ void gather_kernel(const float* __restrict__ enc, const int* __restrict__ order,
                              unsigned short* __restrict__ enc_s){
  int b = blockIdx.y;
  int i = (blockIdx.x * 256 + threadIdx.x) * 4;
  const float4 v = *(const float4*)(enc + (size_t)order[b] * (P_ * ENC_) + i);
  short4v r;
  r[0] = (short)f2bf(v.x); r[1] = (short)f2bf(v.y);
  r[2] = (short)f2bf(v.z); r[3] = (short)f2bf(v.w);
  *(short4v*)(enc_s + (size_t)b * (P_ * ENC_) + i) = r;
}

// ---------------- weight conversion/packing + state init ----------------
__global__ void prep_kernel(const float* __restrict__ We, const float* __restrict__ Wd,
                            const float* __restrict__ Wbeta,
                            const float* __restrict__ W_ih, const float* __restrict__ W_hh,
                            const float* __restrict__ Wfc,
                            const float* __restrict__ bd, const float* __restrict__ bbeta,
                            const float* __restrict__ b_ih, const float* __restrict__ b_hh,
                            unsigned short* __restrict__ We_b, unsigned short* __restrict__ Wpre_b,
                            unsigned short* __restrict__ Wg_b, unsigned short* __restrict__ Wfc_b,
                            float* __restrict__ bias_pre, float* __restrict__ bias_g,
                            float* __restrict__ h, float* __restrict__ c,
                            unsigned short* __restrict__ h_b, unsigned short* __restrict__ xh){
  unsigned int idx = blockIdx.x * blockDim.x + threadIdx.x;
  unsigned int stride = gridDim.x * blockDim.x;
  // We_b: 512x2048 direct
  for (unsigned int i = idx; i < 512u * 2048u; i += stride) We_b[i] = f2bf(We[i]);
  // Wpre_b = [Wd(512x512) ; Wbeta(2048x512)] flat concat (K matches)
  for (unsigned int i = idx; i < 2560u * 512u; i += stride)
    Wpre_b[i] = f2bf(i < 512u * 512u ? Wd[i] : Wbeta[i - 512u * 512u]);
  // Wg_b rows: [W_ih row(2560) | W_hh row(512)] -> 2048 x 3072
  for (unsigned int i = idx; i < 2048u * 3072u; i += stride){
    unsigned int j = i / 3072u, k = i - j * 3072u;
    Wg_b[i] = f2bf(k < 2560u ? W_ih[j * 2560u + k] : W_hh[j * 512u + (k - 2560u)]);
  }
  // Wfc_b: 10000x512 direct
  for (unsigned int i = idx; i < 10000u * 512u; i += stride) Wfc_b[i] = f2bf(Wfc[i]);
  // biases
  for (unsigned int i = idx; i < 2560u; i += stride) bias_pre[i] = (i < 512u) ? bd[i] : bbeta[i - 512u];
  for (unsigned int i = idx; i < 2048u; i += stride) bias_g[i] = b_ih[i] + b_hh[i];
  // state init
  for (unsigned int i = idx; i < (unsigned)B_ * D_; i += stride){
    h[i] = 0.f; c[i] = 0.f; h_b[i] = 0;
    unsigned int b = i >> 9, d = i & 511u;
    xh[(size_t)b * 3072 + 2560 + d] = 0;
  }
}

// ---------------- 256-thread GEMM core: C(128x128) = A(MxK) @ B(NxK)^T -------
#define GEMM_CORE(Aptr, LDA, Bptr, LDB, KDIM, NCLAMP)                         \
  int tid = threadIdx.x; int lane = tid & 63; int w = tid >> 6;               \
  const floatx4 vzero = {0.f,0.f,0.f,0.f};                                    \
  floatx4 acc[4][4];                                                          \
  _Pragma("unroll") for (int i_=0;i_<4;i_++)                                  \
  _Pragma("unroll") for (int j_=0;j_<4;j_++) acc[i_][j_]=vzero;               \
  int mbase=(w&1)<<6, nbase=(w>>1)<<6;                                        \
  int fr=lane&15, fk=(lane>>4)<<3;                                            \
  for (int k0=0;k0<(KDIM);k0+=32){                                            \
    _Pragma("unroll") for (int r_=0;r_<2;r_++){                               \
      int chunk=r_*256+tid; int row=chunk>>2, kc=(chunk&3)<<3;                \
      short8 av=*(const short8*)((Aptr)+(size_t)(m0+row)*(LDA)+k0+kc);        \
      int bn=n0+row; if(bn>(NCLAMP)) bn=(NCLAMP);                             \
      short8 bv=*(const short8*)((Bptr)+(size_t)bn*(LDB)+k0+kc);              \
      *(short8*)&As[chunk*8]=av; *(short8*)&Bs[chunk*8]=bv; }                 \
    __syncthreads();                                                          \
    short8 af[4], bfrag[4];                                                   \
    _Pragma("unroll") for (int i_=0;i_<4;i_++){                               \
      af[i_]=*(const short8*)&As[(mbase+i_*16+fr)*32+fk];                     \
      bfrag[i_]=*(const short8*)&Bs[(nbase+i_*16+fr)*32+fk]; }                \
    _Pragma("unroll") for (int mi_=0;mi_<4;mi_++)                             \
    _Pragma("unroll") for (int ni_=0;ni_<4;ni_++)                             \
      acc[mi_][ni_]=__builtin_amdgcn_mfma_f32_16x16x32_bf16(af[mi_],bfrag[ni_],acc[mi_][ni_],0,0,0); \
    __syncthreads(); }

// ---------------- generic GEMM ----------------
// epi 0: split-K plain stores: Cf[z][m][col] = partial (no init, no atomics)
// epi 1: Cb[m,n] = bf16(acc + bias[n])
__launch_bounds__(256)
__global__ void gemm_bf16(const unsigned short* __restrict__ A, int lda,
                          const unsigned short* __restrict__ Bm, int ldb,
                          const float* __restrict__ bias,
                          float* __restrict__ Cf, unsigned short* __restrict__ Cb, int ldc,
                          int N, int ksz, int epi)
{
  __shared__ unsigned short As[128 * 32];
  __shared__ unsigned short Bs[128 * 32];
  int m0 = blockIdx.y * 128, n0 = blockIdx.x * 128;
  int kb = blockIdx.z * ksz;
  const unsigned short* Ap = A + kb;
  const unsigned short* Bp = Bm + kb;
  GEMM_CORE(Ap, lda, Bp, ldb, ksz, N - 1)
  float* Cz = Cf + (size_t)blockIdx.z * ((size_t)B_ * ldc);
#pragma unroll
  for (int mi = 0; mi < 4; mi++)
#pragma unroll
    for (int ni = 0; ni < 4; ni++){
      floatx4 v = acc[mi][ni];
      int col = n0 + nbase + ni * 16 + fr;
      int rb = m0 + mbase + mi * 16 + ((lane >> 4) << 2);
      if (epi == 0){
#pragma unroll
        for (int r = 0; r < 4; r++)
          Cz[(size_t)(rb + r) * ldc + col] = v[r];
      } else {
        float bb = bias[col];
#pragma unroll
        for (int r = 0; r < 4; r++)
          Cb[(size_t)(rb + r) * ldc + col] = f2bf(v[r] + bb);
      }
    }
}

// ---------------- fused attention: scores + softmax + awe + gate -> xh ------
// grid (2, 128) x 1024 threads. Reads pre-activation as Σz ppart[z] + bias_pre.
__launch_bounds__(1024)
__global__ void attn_kernel(const unsigned short* __restrict__ enc_att,
                            const unsigned short* __restrict__ enc_s,
                            const float* __restrict__ ppart,      // [4][128][2560]
                            const float* __restrict__ bias_pre,
                            const float* __restrict__ wf, const float* __restrict__ bfp,
                            const float* __restrict__ emb, const int* __restrict__ caps_sorted,
                            unsigned short* __restrict__ xh,
                            int t){
  __shared__ float sc[P_];
  __shared__ float al[P_];
  __shared__ float red[256];
  __shared__ float part2[8][128][8];   // 32 KB
  int b = blockIdx.y, bx = blockIdx.x, tid = threadIdx.x;

  // ---- phase 1: scores ----
  int wid = tid >> 6, lane = tid & 63;
  float dav[8], wfv[8];
  {
    const float* bp = bias_pre + lane * 8;
    const float* p0 = ppart + (size_t)b * 2560 + lane * 8;
#pragma unroll
    for (int j = 0; j < 8; j++){
      float s = bp[j];
#pragma unroll
      for (int z = 0; z < 4; z++) s += p0[(size_t)z * (B_ * 2560) + j];
      dav[j] = s;
    }
    *(float4*)&wfv[0] = *(const float4*)(wf + lane * 8);
    *(float4*)&wfv[4] = *(const float4*)(wf + lane * 8 + 4);
  }
  float bfv = bfp[0];
  for (int p = wid; p < P_; p += 16){
    short8 e = *(const short8*)(enc_att + ((size_t)b * P_ + p) * A_ + lane * 8);
    float s = 0.f;
#pragma unroll
    for (int j = 0; j < 8; j++){
      float v = bf2f((unsigned short)e[j]) + dav[j];
      s += fmaxf(v, 0.f) * wfv[j];
    }
#pragma unroll
    for (int off = 32; off > 0; off >>= 1) s += __shfl_down(s, off);
    if (lane == 0) sc[p] = s + bfv;
  }
  __syncthreads();

  // ---- phase 2: softmax over 196 ----
  if (tid < 256) red[tid] = (tid < P_) ? sc[tid] : -1e30f;
  __syncthreads();
  for (int s = 128; s > 0; s >>= 1){ if (tid < s) red[tid] = fmaxf(red[tid], red[tid + s]); __syncthreads(); }
  float mx = red[0];
  __syncthreads();
  float ex = 0.f;
  if (tid < 256){ ex = (tid < P_) ? expf(sc[tid] - mx) : 0.f; red[tid] = ex; }
  __syncthreads();
  for (int s = 128; s > 0; s >>= 1){ if (tid < s) red[tid] += red[tid + s]; __syncthreads(); }
  float inv = 1.f / red[0];
  if (tid < P_) al[tid] = ex * inv;
  __syncthreads();

  // ---- phase 3: awe with 8-way p split, 16B loads ----
  int pg = tid >> 7, et = tid & 127;
  int e0 = bx * 1024 + et * 8;
  const unsigned short* encb = enc_s + (size_t)b * (P_ * ENC_) + e0;
  float aa[8];
#pragma unroll
  for (int j = 0; j < 8; j++) aa[j] = 0.f;
  int pbeg = (pg * 196) >> 3, pend = ((pg + 1) * 196) >> 3;
#pragma unroll 5
  for (int p = pbeg; p < pend; p++){
    float a = al[p];
    short8 v = *(const short8*)(encb + (size_t)p * ENC_);
#pragma unroll
    for (int j = 0; j < 8; j++)
      aa[j] += a * bf2f((unsigned short)v[j]);
  }
#pragma unroll
  for (int j = 0; j < 8; j++) part2[pg][et][j] = aa[j];
  __syncthreads();
  if (pg == 0){
    float s[8];
#pragma unroll
    for (int j = 0; j < 8; j++){
      float acc = 0.f;
#pragma unroll
      for (int g = 0; g < 8; g++) acc += part2[g][et][j];
      s[j] = acc;
    }
    const float* bp = bias_pre + 512 + e0;
    const float* p0 = ppart + (size_t)b * 2560 + 512 + e0;
    short8 r;
#pragma unroll
    for (int j = 0; j < 8; j++){
      float g = bp[j];
#pragma unroll
      for (int z = 0; z < 4; z++) g += p0[(size_t)z * (B_ * 2560) + j];
      r[j] = (short)f2bf(sigf(g) * s[j]);
    }
    *(short8*)(xh + (size_t)b * 3072 + 512 + e0) = r;
  }
  // emb gather for this step's token into xh[:512]
  if (bx == 1 && tid < 512){
    int tok = caps_sorted[b * L_ + t];
    xh[(size_t)b * 3072 + tid] = f2bf(emb[(size_t)tok * E_ + tid]);
  }
}

// ---------------- LSTM pointwise: gates = Σz gpart[z] + bias_g ----------------
__global__ void lstm_kernel(const float* __restrict__ gpart,   // [4][128][2048]
                            const float* __restrict__ bias_g,
                            float* __restrict__ h, float* __restrict__ c,
                            unsigned short* __restrict__ h_b, unsigned short* __restrict__ xh,
                            unsigned short* __restrict__ hnew_b,
                            const int* __restrict__ dec_len, int t){
  int idx = blockIdx.x * 256 + threadIdx.x;   // 65536 total
  int b = idx >> 9, d = idx & 511;
  const float* gr = gpart + (size_t)b * 2048;
  float i_ = bias_g[d], f_ = bias_g[512 + d], g_ = bias_g[1024 + d], o_ = bias_g[1536 + d];
#pragma unroll
  for (int z = 0; z < 4; z++){
    const float* gz = gr + (size_t)z * (B_ * 2048);
    i_ += gz[d]; f_ += gz[512 + d]; g_ += gz[1024 + d]; o_ += gz[1536 + d];
  }
  float cn = sigf(f_) * c[idx] + sigf(i_) * tanhf(g_);
  float hn = sigf(o_) * tanhf(cn);
  bool act = t < dec_len[b];
  float hv = act ? hn : h[idx];
  float cv = act ? cn : c[idx];
  h[idx] = hv; c[idx] = cv;
  unsigned short hvb = f2bf(hv);
  h_b[idx] = hvb;
  xh[(size_t)b * 3072 + 2560 + d] = hvb;
  hnew_b[(size_t)t * (B_ * D_) + idx] = f2bf(hn);
}

// ---------------- preds GEMM: XCD-rect partition + LDS-staged stores ---------
__launch_bounds__(256)
__global__ void gemm_preds(const unsigned short* __restrict__ A,    // hnew_b 6528x512
                           const unsigned short* __restrict__ Bm,   // Wfc_b 10000x512
                           const float* __restrict__ bias,
                           float* __restrict__ Cf,
                           const int* __restrict__ dec_len){
  __shared__ __attribute__((aligned(16))) char smem[4 * 64 * 68 * 4];
  unsigned short* As = (unsigned short*)smem;
  unsigned short* Bs = (unsigned short*)(smem + 8192);
  int bid = blockIdx.x;
  int xcd = bid & 7, i = bid >> 3;          // i in [0,520)
  int mchunk = xcd >> 1, nchunk = xcd & 1;
  int mi_ = i % 13, ni_ = i / 13;
  int mt = mchunk * 13 + mi_;
  int nt = nchunk * 40 + ni_;
  if (mt >= 51 || nt >= 79) return;
  int m0 = mt * 128, n0 = nt * 128;
  GEMM_CORE(A, D_, Bm, D_, D_, V_ - 1)
  float* Cs = (float*)smem + (size_t)w * (64 * 68);
#pragma unroll
  for (int mi = 0; mi < 4; mi++)
#pragma unroll
    for (int ni = 0; ni < 4; ni++){
      int lc = ni * 16 + fr;
      int col = n0 + nbase + lc;
      float bb = bias[col < V_ ? col : V_ - 1];
#pragma unroll
      for (int r = 0; r < 4; r++){
        int lr = mi * 16 + ((lane >> 4) << 2) + r;
        Cs[lr * 68 + lc] = acc[mi][ni][r] + bb;
      }
    }
#pragma unroll
  for (int rd = 0; rd < 16; rd++){
    int lr = rd * 4 + (lane >> 4);
    int m = m0 + mbase + lr;
    int tt = m >> 7, b = m & 127;
    int col = n0 + nbase + fr * 4;
    floatx4 v = *(const floatx4*)&Cs[lr * 68 + fr * 4];
    if (tt >= dec_len[b]){ v[0] = 0.f; v[1] = 0.f; v[2] = 0.f; v[3] = 0.f; }
    if (col < V_)
      __builtin_nontemporal_store(v, (floatx4*)(Cf + ((size_t)b * T_ + tt) * V_ + col));
  }
}

extern "C" void kernel_launch(void* const* d_in, const int* in_sizes, int n_in,
                              void* d_out, int out_size, void* d_ws, size_t ws_size,
                              hipStream_t stream) {
  const float* encoder_out = (const float*)d_in[0];
  const int*   caps        = (const int*)d_in[1];
  const int*   cap_len     = (const int*)d_in[2];
  const float* emb         = (const float*)d_in[3];
  const float* We          = (const float*)d_in[4];
  const float* be          = (const float*)d_in[5];
  const float* Wd          = (const float*)d_in[6];
  const float* bd          = (const float*)d_in[7];
  const float* wf          = (const float*)d_in[8];
  const float* bf          = (const float*)d_in[9];
  const float* W_ih        = (const float*)d_in[10];
  const float* b_ih        = (const float*)d_in[11];
  const float* W_hh        = (const float*)d_in[12];
  const float* b_hh        = (const float*)d_in[13];
  const float* Wbeta       = (const float*)d_in[14];
  const float* bbeta       = (const float*)d_in[15];
  const float* Wfc         = (const float*)d_in[16];
  const float* bfc         = (const float*)d_in[17];

  float* out_preds  = (float*)d_out;
  float* out_caps   = out_preds + (size_t)B_ * T_ * V_;
  float* out_declen = out_caps + (size_t)B_ * L_;

  char* w = (char*)d_ws;
  auto alloc = [&](size_t bytes) -> void* {
    void* p = (void*)w;
    w += (bytes + 255) & ~(size_t)255;
    return p;
  };
  int*   order       = (int*)alloc(B_ * 4);
  int*   dec_len     = (int*)alloc(B_ * 4);
  int*   caps_sorted = (int*)alloc((size_t)B_ * L_ * 4);
  unsigned short* enc_s   = (unsigned short*)alloc((size_t)B_ * P_ * ENC_ * 2);
  unsigned short* We_b    = (unsigned short*)alloc((size_t)512 * 2048 * 2);
  unsigned short* Wpre_b  = (unsigned short*)alloc((size_t)2560 * 512 * 2);
  unsigned short* Wg_b    = (unsigned short*)alloc((size_t)2048 * 3072 * 2);
  unsigned short* Wfc_b   = (unsigned short*)alloc((size_t)10000 * 512 * 2);
  unsigned short* enc_att = (unsigned short*)alloc((size_t)B_ * P_ * A_ * 2);
  float* bias_pre    = (float*)alloc(2560 * 4);
  float* bias_g      = (float*)alloc(2048 * 4);
  float* ppart       = (float*)alloc((size_t)4 * B_ * 2560 * 4);
  float* gpart       = (float*)alloc((size_t)4 * B_ * 2048 * 4);
  unsigned short* xh = (unsigned short*)alloc((size_t)B_ * 3072 * 2);
  float* h           = (float*)alloc((size_t)B_ * D_ * 4);
  float* c           = (float*)alloc((size_t)B_ * D_ * 4);
  unsigned short* h_b = (unsigned short*)alloc((size_t)B_ * D_ * 2);
  unsigned short* hnew_b = (unsigned short*)alloc((size_t)T_ * B_ * D_ * 2);

  sort_kernel<<<1, 128, 0, stream>>>(cap_len, caps, order, dec_len, caps_sorted, out_caps, out_declen);
  gather_kernel<<<dim3(392, 128), 256, 0, stream>>>(encoder_out, order, enc_s);
  prep_kernel<<<2048, 256, 0, stream>>>(We, Wd, Wbeta, W_ih, W_hh, Wfc, bd, bbeta, b_ih, b_hh,
                                        We_b, Wpre_b, Wg_b, Wfc_b, bias_pre, bias_g,
                                        h, c, h_b, xh);

  // enc_att = enc_s @ We^T + be -> bf16 : M=25088, N=512, K=2048
  gemm_bf16<<<dim3(4, 196, 1), 256, 0, stream>>>(
      enc_s, ENC_, We_b, ENC_, be, nullptr, enc_att, A_, A_, ENC_, 1);

  for (int t = 0; t < T_; t++){
    // ppart[z] = h @ [Wd;Wbeta]^T  K-slice (plain stores)
    gemm_bf16<<<dim3(20, 1, 4), 256, 0, stream>>>(
        h_b, D_, Wpre_b, D_, nullptr, ppart, nullptr, 2560, 2560, 128, 0);

    // attention (sums ppart slices + bias) -> xh = [emb | gate*awe]
    attn_kernel<<<dim3(2, B_), 1024, 0, stream>>>(enc_att, enc_s, ppart, bias_pre, wf, bf,
                                                  emb, caps_sorted, xh, t);

    // gpart[z] = xh @ [W_ih|W_hh]^T  K-slice (plain stores)
    gemm_bf16<<<dim3(16, 1, 4), 256, 0, stream>>>(
        xh, 3072, Wg_b, 3072, nullptr, gpart, nullptr, 2048, 2048, 768, 0);

    // lstm sums gpart slices + bias_g
    lstm_kernel<<<(B_ * D_) / 256, 256, 0, stream>>>(gpart, bias_g, h, c, h_b, xh, hnew_b,
                                                     dec_len, t);
  }

  // preds: (T*B, V) = hnew @ Wfc^T + bfc, masked + scattered to (B,T,V)
  gemm_preds<<<4160, 256, 0, stream>>>(hnew_b, Wfc_b, bfc, out_preds, dec_len);
}

// Round 8
// 3394.276 us; speedup vs baseline: 4.5460x; 1.1165x over previous
//
#include <hip/hip_runtime.h>
#include <cstdint>
#include <cstddef>

#define B_ 128
#define P_ 196
#define ENC_ 2048
#define A_ 512
#define E_ 512
#define D_ 512
#define V_ 10000
#define L_ 52
#define T_ 51
#define ZPRE 8   // split-K slices for pre-GEMM (K=512 -> 64/slice)
#define ZG 8     // split-K slices for gates GEMM (K=3072 -> 384/slice)

using short8 = __attribute__((ext_vector_type(8))) short;
using short4v = __attribute__((ext_vector_type(4))) short;
using floatx4 = __attribute__((ext_vector_type(4))) float;

__device__ __forceinline__ float sigf(float x){ return 1.f/(1.f+expf(-x)); }

__device__ __forceinline__ unsigned short f2bf(float f){
  unsigned int u = __float_as_uint(f);
  unsigned int r = (u + 0x7fffu + ((u >> 16) & 1u)) >> 16;
  return (unsigned short)r;
}
__device__ __forceinline__ float bf2f(unsigned short u){
  return __uint_as_float(((unsigned int)u) << 16);
}

// ---------------- sort (stable descending by length) ----------------
__global__ void sort_kernel(const int* __restrict__ cap_len, const int* __restrict__ caps,
                            int* __restrict__ order, int* __restrict__ dec_len,
                            int* __restrict__ caps_sorted,
                            float* __restrict__ out_caps, float* __restrict__ out_declen){
  __shared__ int len_s[B_];
  int i = threadIdx.x;
  len_s[i] = cap_len[i];
  __syncthreads();
  int li = len_s[i];
  int pos = 0;
  for (int j = 0; j < B_; j++){
    int lj = len_s[j];
    pos += (lj > li) || (lj == li && j < i);
  }
  order[pos] = i;
  dec_len[pos] = li - 1;
  out_declen[pos] = (float)(li - 1);
  for (int l = 0; l < L_; l++){
    int v = caps[i * L_ + l];
    caps_sorted[pos * L_ + l] = v;
    out_caps[pos * L_ + l] = (float)v;
  }
}

// ---------------- enc gather + fp32->bf16 ----------------
__global__ void gather_kernel(const float* __restrict__ enc, const int* __restrict__ order,
                              unsigned short* __restrict__ enc_s){
  int b = blockIdx.y;
  int i = (blockIdx.x * 256 + threadIdx.x) * 4;
  const float4 v = *(const float4*)(enc + (size_t)order[b] * (P_ * ENC_) + i);
  short4v r;
  r[0] = (short)f2bf(v.x); r[1] = (short)f2bf(v.y);
  r[2] = (short)f2bf(v.z); r[3] = (short)f2bf(v.w);
  *(short4v*)(enc_s + (size_t)b * (P_ * ENC_) + i) = r;
}

// ---------------- weight conversion/packing + state init ----------------
__global__ void prep_kernel(const float* __restrict__ We, const float* __restrict__ Wd,
                            const float* __restrict__ Wbeta,
                            const float* __restrict__ W_ih, const float* __restrict__ W_hh,
                            const float* __restrict__ Wfc,
                            const float* __restrict__ bd, const float* __restrict__ bbeta,
                            const float* __restrict__ b_ih, const float* __restrict__ b_hh,
                            unsigned short* __restrict__ We_b, unsigned short* __restrict__ Wpre_b,
                            unsigned short* __restrict__ Wg_b, unsigned short* __restrict__ Wfc_b,
                            float* __restrict__ bias_pre, float* __restrict__ bias_g,
                            float* __restrict__ h, float* __restrict__ c,
                            unsigned short* __restrict__ h_b, unsigned short* __restrict__ xh){
  unsigned int idx = blockIdx.x * blockDim.x + threadIdx.x;
  unsigned int stride = gridDim.x * blockDim.x;
  // We_b: 512x2048 direct
  for (unsigned int i = idx; i < 512u * 2048u; i += stride) We_b[i] = f2bf(We[i]);
  // Wpre_b = [Wd(512x512) ; Wbeta(2048x512)] flat concat (K matches)
  for (unsigned int i = idx; i < 2560u * 512u; i += stride)
    Wpre_b[i] = f2bf(i < 512u * 512u ? Wd[i] : Wbeta[i - 512u * 512u]);
  // Wg_b rows: [W_ih row(2560) | W_hh row(512)] -> 2048 x 3072
  for (unsigned int i = idx; i < 2048u * 3072u; i += stride){
    unsigned int j = i / 3072u, k = i - j * 3072u;
    Wg_b[i] = f2bf(k < 2560u ? W_ih[j * 2560u + k] : W_hh[j * 512u + (k - 2560u)]);
  }
  // Wfc_b: 10000x512 direct
  for (unsigned int i = idx; i < 10000u * 512u; i += stride) Wfc_b[i] = f2bf(Wfc[i]);
  // biases
  for (unsigned int i = idx; i < 2560u; i += stride) bias_pre[i] = (i < 512u) ? bd[i] : bbeta[i - 512u];
  for (unsigned int i = idx; i < 2048u; i += stride) bias_g[i] = b_ih[i] + b_hh[i];
  // state init
  for (unsigned int i = idx; i < (unsigned)B_ * D_; i += stride){
    h[i] = 0.f; c[i] = 0.f; h_b[i] = 0;
    unsigned int b = i >> 9, d = i & 511u;
    xh[(size_t)b * 3072 + 2560 + d] = 0;
  }
}

// ---------------- 256-thread GEMM core: C(128x128) = A(MxK) @ B(NxK)^T -------
#define GEMM_CORE(Aptr, LDA, Bptr, LDB, KDIM, NCLAMP)                         \
  int tid = threadIdx.x; int lane = tid & 63; int w = tid >> 6;               \
  const floatx4 vzero = {0.f,0.f,0.f,0.f};                                    \
  floatx4 acc[4][4];                                                          \
  _Pragma("unroll") for (int i_=0;i_<4;i_++)                                  \
  _Pragma("unroll") for (int j_=0;j_<4;j_++) acc[i_][j_]=vzero;               \
  int mbase=(w&1)<<6, nbase=(w>>1)<<6;                                        \
  int fr=lane&15, fk=(lane>>4)<<3;                                            \
  for (int k0=0;k0<(KDIM);k0+=32){                                            \
    _Pragma("unroll") for (int r_=0;r_<2;r_++){                               \
      int chunk=r_*256+tid; int row=chunk>>2, kc=(chunk&3)<<3;                \
      short8 av=*(const short8*)((Aptr)+(size_t)(m0+row)*(LDA)+k0+kc);        \
      int bn=n0+row; if(bn>(NCLAMP)) bn=(NCLAMP);                             \
      short8 bv=*(const short8*)((Bptr)+(size_t)bn*(LDB)+k0+kc);              \
      *(short8*)&As[chunk*8]=av; *(short8*)&Bs[chunk*8]=bv; }                 \
    __syncthreads();                                                          \
    short8 af[4], bfrag[4];                                                   \
    _Pragma("unroll") for (int i_=0;i_<4;i_++){                               \
      af[i_]=*(const short8*)&As[(mbase+i_*16+fr)*32+fk];                     \
      bfrag[i_]=*(const short8*)&Bs[(nbase+i_*16+fr)*32+fk]; }                \
    _Pragma("unroll") for (int mi_=0;mi_<4;mi_++)                             \
    _Pragma("unroll") for (int ni_=0;ni_<4;ni_++)                             \
      acc[mi_][ni_]=__builtin_amdgcn_mfma_f32_16x16x32_bf16(af[mi_],bfrag[ni_],acc[mi_][ni_],0,0,0); \
    __syncthreads(); }

// ---------------- generic GEMM ----------------
// epi 0: split-K plain stores: Cf[z][m][col] = partial (no init, no atomics)
// epi 1: Cb[m,n] = bf16(acc + bias[n])
__launch_bounds__(256)
__global__ void gemm_bf16(const unsigned short* __restrict__ A, int lda,
                          const unsigned short* __restrict__ Bm, int ldb,
                          const float* __restrict__ bias,
                          float* __restrict__ Cf, unsigned short* __restrict__ Cb, int ldc,
                          int N, int ksz, int epi)
{
  __shared__ unsigned short As[128 * 32];
  __shared__ unsigned short Bs[128 * 32];
  int m0 = blockIdx.y * 128, n0 = blockIdx.x * 128;
  int kb = blockIdx.z * ksz;
  const unsigned short* Ap = A + kb;
  const unsigned short* Bp = Bm + kb;
  GEMM_CORE(Ap, lda, Bp, ldb, ksz, N - 1)
  float* Cz = Cf + (size_t)blockIdx.z * ((size_t)B_ * ldc);
#pragma unroll
  for (int mi = 0; mi < 4; mi++)
#pragma unroll
    for (int ni = 0; ni < 4; ni++){
      floatx4 v = acc[mi][ni];
      int col = n0 + nbase + ni * 16 + fr;
      int rb = m0 + mbase + mi * 16 + ((lane >> 4) << 2);
      if (epi == 0){
#pragma unroll
        for (int r = 0; r < 4; r++)
          Cz[(size_t)(rb + r) * ldc + col] = v[r];
      } else {
        float bb = bias[col];
#pragma unroll
        for (int r = 0; r < 4; r++)
          Cb[(size_t)(rb + r) * ldc + col] = f2bf(v[r] + bb);
      }
    }
}

// ---------------- fused attention: scores + softmax + awe + gate -> xh ------
// grid (2, 128) x 1024 threads. Reads pre-activation as Σz ppart[z] + bias_pre.
__launch_bounds__(1024)
__global__ void attn_kernel(const unsigned short* __restrict__ enc_att,
                            const unsigned short* __restrict__ enc_s,
                            const float* __restrict__ ppart,      // [ZPRE][128][2560]
                            const float* __restrict__ bias_pre,
                            const float* __restrict__ wf, const float* __restrict__ bfp,
                            const float* __restrict__ emb, const int* __restrict__ caps_sorted,
                            unsigned short* __restrict__ xh,
                            int t){
  __shared__ float sc[P_];
  __shared__ float al[P_];
  __shared__ float red[256];
  __shared__ float part2[8][128][8];   // 32 KB
  int b = blockIdx.y, bx = blockIdx.x, tid = threadIdx.x;

  // ---- phase 1: scores ----
  int wid = tid >> 6, lane = tid & 63;
  float dav[8], wfv[8];
  {
    const float* bp = bias_pre + lane * 8;
    const float* p0 = ppart + (size_t)b * 2560 + lane * 8;
#pragma unroll
    for (int j = 0; j < 8; j++){
      float s = bp[j];
#pragma unroll
      for (int z = 0; z < ZPRE; z++) s += p0[(size_t)z * (B_ * 2560) + j];
      dav[j] = s;
    }
    *(float4*)&wfv[0] = *(const float4*)(wf + lane * 8);
    *(float4*)&wfv[4] = *(const float4*)(wf + lane * 8 + 4);
  }
  float bfv = bfp[0];
  for (int p = wid; p < P_; p += 16){
    short8 e = *(const short8*)(enc_att + ((size_t)b * P_ + p) * A_ + lane * 8);
    float s = 0.f;
#pragma unroll
    for (int j = 0; j < 8; j++){
      float v = bf2f((unsigned short)e[j]) + dav[j];
      s += fmaxf(v, 0.f) * wfv[j];
    }
#pragma unroll
    for (int off = 32; off > 0; off >>= 1) s += __shfl_down(s, off);
    if (lane == 0) sc[p] = s + bfv;
  }
  __syncthreads();

  // ---- phase 2: softmax over 196 ----
  if (tid < 256) red[tid] = (tid < P_) ? sc[tid] : -1e30f;
  __syncthreads();
  for (int s = 128; s > 0; s >>= 1){ if (tid < s) red[tid] = fmaxf(red[tid], red[tid + s]); __syncthreads(); }
  float mx = red[0];
  __syncthreads();
  float ex = 0.f;
  if (tid < 256){ ex = (tid < P_) ? expf(sc[tid] - mx) : 0.f; red[tid] = ex; }
  __syncthreads();
  for (int s = 128; s > 0; s >>= 1){ if (tid < s) red[tid] += red[tid + s]; __syncthreads(); }
  float inv = 1.f / red[0];
  if (tid < P_) al[tid] = ex * inv;
  __syncthreads();

  // ---- phase 3: awe with 8-way p split, 16B loads ----
  int pg = tid >> 7, et = tid & 127;
  int e0 = bx * 1024 + et * 8;
  const unsigned short* encb = enc_s + (size_t)b * (P_ * ENC_) + e0;
  float aa[8];
#pragma unroll
  for (int j = 0; j < 8; j++) aa[j] = 0.f;
  int pbeg = (pg * 196) >> 3, pend = ((pg + 1) * 196) >> 3;
#pragma unroll 5
  for (int p = pbeg; p < pend; p++){
    float a = al[p];
    short8 v = *(const short8*)(encb + (size_t)p * ENC_);
#pragma unroll
    for (int j = 0; j < 8; j++)
      aa[j] += a * bf2f((unsigned short)v[j]);
  }
#pragma unroll
  for (int j = 0; j < 8; j++) part2[pg][et][j] = aa[j];
  __syncthreads();
  if (pg == 0){
    float s[8];
#pragma unroll
    for (int j = 0; j < 8; j++){
      float acc = 0.f;
#pragma unroll
      for (int g = 0; g < 8; g++) acc += part2[g][et][j];
      s[j] = acc;
    }
    const float* bp = bias_pre + 512 + e0;
    const float* p0 = ppart + (size_t)b * 2560 + 512 + e0;
    short8 r;
#pragma unroll
    for (int j = 0; j < 8; j++){
      float g = bp[j];
#pragma unroll
      for (int z = 0; z < ZPRE; z++) g += p0[(size_t)z * (B_ * 2560) + j];
      r[j] = (short)f2bf(sigf(g) * s[j]);
    }
    *(short8*)(xh + (size_t)b * 3072 + 512 + e0) = r;
  }
  // emb gather for this step's token into xh[:512]
  if (bx == 1 && tid < 512){
    int tok = caps_sorted[b * L_ + t];
    xh[(size_t)b * 3072 + tid] = f2bf(emb[(size_t)tok * E_ + tid]);
  }
}

// ---------------- LSTM pointwise: gates = Σz gpart[z] + bias_g ----------------
__global__ void lstm_kernel(const float* __restrict__ gpart,   // [ZG][128][2048]
                            const float* __restrict__ bias_g,
                            float* __restrict__ h, float* __restrict__ c,
                            unsigned short* __restrict__ h_b, unsigned short* __restrict__ xh,
                            unsigned short* __restrict__ hnew_b,
                            const int* __restrict__ dec_len, int t){
  int idx = blockIdx.x * 256 + threadIdx.x;   // 65536 total
  int b = idx >> 9, d = idx & 511;
  const float* gr = gpart + (size_t)b * 2048;
  float i_ = bias_g[d], f_ = bias_g[512 + d], g_ = bias_g[1024 + d], o_ = bias_g[1536 + d];
#pragma unroll
  for (int z = 0; z < ZG; z++){
    const float* gz = gr + (size_t)z * (B_ * 2048);
    i_ += gz[d]; f_ += gz[512 + d]; g_ += gz[1024 + d]; o_ += gz[1536 + d];
  }
  float cn = sigf(f_) * c[idx] + sigf(i_) * tanhf(g_);
  float hn = sigf(o_) * tanhf(cn);
  bool act = t < dec_len[b];
  float hv = act ? hn : h[idx];
  float cv = act ? cn : c[idx];
  h[idx] = hv; c[idx] = cv;
  unsigned short hvb = f2bf(hv);
  h_b[idx] = hvb;
  xh[(size_t)b * 3072 + 2560 + d] = hvb;
  hnew_b[(size_t)t * (B_ * D_) + idx] = f2bf(hn);
}

// ---------------- preds GEMM: XCD-rect partition + LDS-staged stores ---------
__launch_bounds__(256)
__global__ void gemm_preds(const unsigned short* __restrict__ A,    // hnew_b 6528x512
                           const unsigned short* __restrict__ Bm,   // Wfc_b 10000x512
                           const float* __restrict__ bias,
                           float* __restrict__ Cf,
                           const int* __restrict__ dec_len){
  __shared__ __attribute__((aligned(16))) char smem[4 * 64 * 68 * 4];
  unsigned short* As = (unsigned short*)smem;
  unsigned short* Bs = (unsigned short*)(smem + 8192);
  int bid = blockIdx.x;
  int xcd = bid & 7, i = bid >> 3;          // i in [0,520)
  int mchunk = xcd >> 1, nchunk = xcd & 1;
  int mi_ = i % 13, ni_ = i / 13;
  int mt = mchunk * 13 + mi_;
  int nt = nchunk * 40 + ni_;
  if (mt >= 51 || nt >= 79) return;
  int m0 = mt * 128, n0 = nt * 128;
  GEMM_CORE(A, D_, Bm, D_, D_, V_ - 1)
  float* Cs = (float*)smem + (size_t)w * (64 * 68);
#pragma unroll
  for (int mi = 0; mi < 4; mi++)
#pragma unroll
    for (int ni = 0; ni < 4; ni++){
      int lc = ni * 16 + fr;
      int col = n0 + nbase + lc;
      float bb = bias[col < V_ ? col : V_ - 1];
#pragma unroll
      for (int r = 0; r < 4; r++){
        int lr = mi * 16 + ((lane >> 4) << 2) + r;
        Cs[lr * 68 + lc] = acc[mi][ni][r] + bb;
      }
    }
#pragma unroll
  for (int rd = 0; rd < 16; rd++){
    int lr = rd * 4 + (lane >> 4);
    int m = m0 + mbase + lr;
    int tt = m >> 7, b = m & 127;
    int col = n0 + nbase + fr * 4;
    floatx4 v = *(const floatx4*)&Cs[lr * 68 + fr * 4];
    if (tt >= dec_len[b]){ v[0] = 0.f; v[1] = 0.f; v[2] = 0.f; v[3] = 0.f; }
    if (col < V_)
      __builtin_nontemporal_store(v, (floatx4*)(Cf + ((size_t)b * T_ + tt) * V_ + col));
  }
}

extern "C" void kernel_launch(void* const* d_in, const int* in_sizes, int n_in,
                              void* d_out, int out_size, void* d_ws, size_t ws_size,
                              hipStream_t stream) {
  const float* encoder_out = (const float*)d_in[0];
  const int*   caps        = (const int*)d_in[1];
  const int*   cap_len     = (const int*)d_in[2];
  const float* emb         = (const float*)d_in[3];
  const float* We          = (const float*)d_in[4];
  const float* be          = (const float*)d_in[5];
  const float* Wd          = (const float*)d_in[6];
  const float* bd          = (const float*)d_in[7];
  const float* wf          = (const float*)d_in[8];
  const float* bf          = (const float*)d_in[9];
  const float* W_ih        = (const float*)d_in[10];
  const float* b_ih        = (const float*)d_in[11];
  const float* W_hh        = (const float*)d_in[12];
  const float* b_hh        = (const float*)d_in[13];
  const float* Wbeta       = (const float*)d_in[14];
  const float* bbeta       = (const float*)d_in[15];
  const float* Wfc         = (const float*)d_in[16];
  const float* bfc         = (const float*)d_in[17];

  float* out_preds  = (float*)d_out;
  float* out_caps   = out_preds + (size_t)B_ * T_ * V_;
  float* out_declen = out_caps + (size_t)B_ * L_;

  char* w = (char*)d_ws;
  auto alloc = [&](size_t bytes) -> void* {
    void* p = (void*)w;
    w += (bytes + 255) & ~(size_t)255;
    return p;
  };
  int*   order       = (int*)alloc(B_ * 4);
  int*   dec_len     = (int*)alloc(B_ * 4);
  int*   caps_sorted = (int*)alloc((size_t)B_ * L_ * 4);
  unsigned short* enc_s   = (unsigned short*)alloc((size_t)B_ * P_ * ENC_ * 2);
  unsigned short* We_b    = (unsigned short*)alloc((size_t)512 * 2048 * 2);
  unsigned short* Wpre_b  = (unsigned short*)alloc((size_t)2560 * 512 * 2);
  unsigned short* Wg_b    = (unsigned short*)alloc((size_t)2048 * 3072 * 2);
  unsigned short* Wfc_b   = (unsigned short*)alloc((size_t)10000 * 512 * 2);
  unsigned short* enc_att = (unsigned short*)alloc((size_t)B_ * P_ * A_ * 2);
  float* bias_pre    = (float*)alloc(2560 * 4);
  float* bias_g      = (float*)alloc(2048 * 4);
  float* ppart       = (float*)alloc((size_t)ZPRE * B_ * 2560 * 4);
  float* gpart       = (float*)alloc((size_t)ZG * B_ * 2048 * 4);
  unsigned short* xh = (unsigned short*)alloc((size_t)B_ * 3072 * 2);
  float* h           = (float*)alloc((size_t)B_ * D_ * 4);
  float* c           = (float*)alloc((size_t)B_ * D_ * 4);
  unsigned short* h_b = (unsigned short*)alloc((size_t)B_ * D_ * 2);
  unsigned short* hnew_b = (unsigned short*)alloc((size_t)T_ * B_ * D_ * 2);

  sort_kernel<<<1, 128, 0, stream>>>(cap_len, caps, order, dec_len, caps_sorted, out_caps, out_declen);
  gather_kernel<<<dim3(392, 128), 256, 0, stream>>>(encoder_out, order, enc_s);
  prep_kernel<<<2048, 256, 0, stream>>>(We, Wd, Wbeta, W_ih, W_hh, Wfc, bd, bbeta, b_ih, b_hh,
                                        We_b, Wpre_b, Wg_b, Wfc_b, bias_pre, bias_g,
                                        h, c, h_b, xh);

  // enc_att = enc_s @ We^T + be -> bf16 : M=25088, N=512, K=2048
  gemm_bf16<<<dim3(4, 196, 1), 256, 0, stream>>>(
      enc_s, ENC_, We_b, ENC_, be, nullptr, enc_att, A_, A_, ENC_, 1);

  for (int t = 0; t < T_; t++){
    // ppart[z] = h @ [Wd;Wbeta]^T  K-slice (plain stores, 2 K-iters/slice)
    gemm_bf16<<<dim3(20, 1, ZPRE), 256, 0, stream>>>(
        h_b, D_, Wpre_b, D_, nullptr, ppart, nullptr, 2560, 2560, 512 / ZPRE, 0);

    // attention (sums ppart slices + bias) -> xh = [emb | gate*awe]
    attn_kernel<<<dim3(2, B_), 1024, 0, stream>>>(enc_att, enc_s, ppart, bias_pre, wf, bf,
                                                  emb, caps_sorted, xh, t);

    // gpart[z] = xh @ [W_ih|W_hh]^T  K-slice (plain stores, 12 K-iters/slice)
    gemm_bf16<<<dim3(16, 1, ZG), 256, 0, stream>>>(
        xh, 3072, Wg_b, 3072, nullptr, gpart, nullptr, 2048, 2048, 3072 / ZG, 0);

    // lstm sums gpart slices + bias_g
    lstm_kernel<<<(B_ * D_) / 256, 256, 0, stream>>>(gpart, bias_g, h, c, h_b, xh, hnew_b,
                                                     dec_len, t);
  }

  // preds: (T*B, V) = hnew @ Wfc^T + bfc, masked + scattered to (B,T,V)
  gemm_preds<<<4160, 256, 0, stream>>>(hnew_b, Wfc_b, bfc, out_preds, dec_len);
}